// Round 19
// baseline (222.195 us; speedup 1.0000x reference)
//
#include <hip/hip_runtime.h>
#include <hip/hip_bf16.h>

typedef unsigned short u16;
typedef __attribute__((ext_vector_type(8))) short short8;
typedef __attribute__((ext_vector_type(4))) float f32x4;

#define N_TOKENS 4096
#define HIDDEN   1024
#define N_EXP    8
#define EXPAND   2048

// ---------- workspace layout (bytes) ----------
#define TOKB_OFF  0ull                   // bf16 tokens      [4096][1024]    8,388,608
#define W1T_OFF   8388608ull             // bf16 w1^T        [8][2048][1024] 33,554,432
#define OBUF_OFF  8388608ull             // bf16 obuf        [8192][1024]    16,777,216 (reuses w1t after ffn1)
#define W2T_OFF   41943040ull            // bf16 w2^T        [8][1024][2048] 33,554,432
#define H_OFF     75497472ull            // bf16 h           [8192][2048]    33,554,432
#define RLT_OFF   109051904ull           // int rowlist_token[8192]
#define RLG_OFF   109084672ull           // float rowlist_gate[8192]
#define CNT_OFF   109117440ull           // int cnt[8]
#define E01_OFF   109117472ull           // int e01[4096][2]
#define GATE_OFF  109183008ull           // float gates[4096][2]
#define ROWS2_OFF 109215776ull           // int rows2[4096][2]

__device__ __forceinline__ u16 f2bf(float f) {
  union { float f; unsigned u; } v; v.f = f;
  unsigned r = v.u + 0x7fffu + ((v.u >> 16) & 1u);   // round-to-nearest-even
  return (u16)(r >> 16);
}

__device__ __forceinline__ float bf2f(u16 b) {
  union { unsigned u; float f; } v; v.u = ((unsigned)b) << 16;
  return v.f;
}

__device__ __forceinline__ void glds16(const void* g, void* l) {
  __builtin_amdgcn_global_load_lds(
      (const __attribute__((address_space(1))) void*)g,
      (__attribute__((address_space(3))) void*)l, 16, 0, 0);
}

__device__ __forceinline__ float gelu_tanh(float x) {
  float u = x * (0.7978845608f + 0.0356774081f * x * x);
  float t = __expf(-2.0f * fabsf(u));
  float th = (1.0f - t) / (1.0f + t);
  th = (u >= 0.0f) ? th : -th;
  return 0.5f * x * (1.0f + th);
}

// ---------- fp32 [E][R][C] -> bf16 [E][C][R]; 64x64 tiles, bf16 in LDS ----------
__global__ __launch_bounds__(256) void cvt_transpose_k(const float* __restrict__ in,
                                                       u16* __restrict__ out,
                                                       int R, int C) {
  __shared__ u16 t[64][66];
  int e = blockIdx.z;
  int c0 = blockIdx.x * 64, r0 = blockIdx.y * 64;
  const float* ip = in + (size_t)e * R * C;
  u16* op = out + (size_t)e * R * C;
  int tid = threadIdx.x;
  #pragma unroll
  for (int i = 0; i < 16; ++i) {
    int flat = i * 256 + tid;
    int row = flat >> 6, col = flat & 63;
    t[row][col] = f2bf(ip[(size_t)(r0 + row) * C + c0 + col]);
  }
  __syncthreads();
  #pragma unroll
  for (int i = 0; i < 16; ++i) {
    int flat = i * 256 + tid;
    int orow = flat >> 6, ocol = flat & 63;       // out row = col-index, 128B stores
    op[(size_t)(c0 + orow) * R + r0 + ocol] = t[ocol][orow];
  }
}

// ---------- logits + top-2 + softmax + fused tokens->bf16 (float4 loads) ----------
__global__ __launch_bounds__(256) void logits_k(const float* __restrict__ tokens,
                                                const float* __restrict__ rw,
                                                const float* __restrict__ rb,
                                                u16* __restrict__ tokb,
                                                int* __restrict__ e01,
                                                float* __restrict__ gates) {
  __shared__ float rwl[N_EXP * HIDDEN];
  int tid = threadIdx.x;
  for (int i = tid; i < N_EXP * HIDDEN / 4; i += 256)
    ((float4*)rwl)[i] = ((const float4*)rw)[i];
  __syncthreads();
  int w = tid >> 6, l = tid & 63;
  int t = blockIdx.x * 4 + w;
  const float* tp = tokens + (size_t)t * HIDDEN;
  u16* tb = tokb + (size_t)t * HIDDEN;
  float acc[8] = {0.f,0.f,0.f,0.f,0.f,0.f,0.f,0.f};
  #pragma unroll
  for (int it = 0; it < 4; ++it) {
    int k = it * 256 + l * 4;
    float4 tv = *(const float4*)&tp[k];
    ushort4 o;
    o.x = f2bf(tv.x); o.y = f2bf(tv.y); o.z = f2bf(tv.z); o.w = f2bf(tv.w);
    *(ushort4*)&tb[k] = o;
    #pragma unroll
    for (int e = 0; e < 8; ++e) {
      const float4 rv = *(const float4*)&rwl[e * HIDDEN + k];
      acc[e] += tv.x * rv.x + tv.y * rv.y + tv.z * rv.z + tv.w * rv.w;
    }
  }
  #pragma unroll
  for (int off = 32; off >= 1; off >>= 1) {
    #pragma unroll
    for (int e = 0; e < 8; ++e) acc[e] += __shfl_xor(acc[e], off);
  }
  if (l == 0) {
    float lg[8];
    #pragma unroll
    for (int e = 0; e < 8; ++e) lg[e] = acc[e] + rb[e];
    int b0 = 0; float v0 = lg[0];
    #pragma unroll
    for (int e = 1; e < 8; ++e) if (lg[e] > v0) { v0 = lg[e]; b0 = e; }
    int b1 = -1; float v1 = -3.4e38f;
    #pragma unroll
    for (int e = 0; e < 8; ++e) {
      if (e == b0) continue;
      if (lg[e] > v1) { v1 = lg[e]; b1 = e; }
    }
    float d = expf(v1 - v0);
    float p1 = d / (1.f + d);
    float p0 = 1.f - p1;
    e01[t * 2] = b0;   e01[t * 2 + 1] = b1;
    gates[t * 2] = p0; gates[t * 2 + 1] = p1;
  }
}

// ---------- deterministic stable counting sort by expert (single block) ----------
__global__ __launch_bounds__(1024) void order_k(const int* __restrict__ e01,
                                                const float* __restrict__ gates,
                                                int* __restrict__ cnt,
                                                int* __restrict__ rlt,
                                                float* __restrict__ rlg,
                                                int* __restrict__ rows2) {
  __shared__ int slotbuf[2 * N_TOKENS];
  __shared__ int wcnt[16][N_EXP];
  __shared__ int base_run[N_EXP];
  __shared__ int basep[N_EXP];
  int tid = threadIdx.x, w = tid >> 6, l = tid & 63;
  if (tid < N_EXP) base_run[tid] = 0;
  __syncthreads();
  unsigned long long ltmask = (1ull << l) - 1ull;
  #pragma unroll
  for (int c = 0; c < 8; ++c) {
    int i = c * 1024 + tid;
    int ei = e01[i];
    int myrank = 0;
    #pragma unroll
    for (int e = 0; e < N_EXP; ++e) {
      unsigned long long b = __ballot(ei == e);
      if (l == 0) wcnt[w][e] = __popcll(b);
      if (ei == e) myrank = __popcll(b & ltmask);
    }
    __syncthreads();
    if (tid < N_EXP) {
      int e = tid, off = base_run[e];
      #pragma unroll
      for (int ww = 0; ww < 16; ++ww) {
        int v = wcnt[ww][e]; wcnt[ww][e] = off; off += v;
      }
      base_run[e] = off;
    }
    __syncthreads();
    slotbuf[i] = wcnt[w][ei] + myrank;
    __syncthreads();
  }
  if (tid < N_EXP) cnt[tid] = base_run[tid];
  if (tid == 0) {
    int s = 0;
    for (int e = 0; e < N_EXP; ++e) { basep[e] = s; s += base_run[e]; }
  }
  __syncthreads();
  #pragma unroll
  for (int c = 0; c < 8; ++c) {
    int i = c * 1024 + tid;
    int e = e01[i];
    int row = basep[e] + slotbuf[i];
    rlt[row] = i >> 1;
    rlg[row] = gates[i];
    rows2[i] = row;
  }
}

// ======= 128x128x32 tile; 4 waves (2x2), wave tile 64x64; 32 KB LDS dbuf =======
// Intensity M*N/(M+N)=32 FLOP/LDS-byte (2x R18). 3 blocks/CU, 3 waves/SIMD.
// Row = 4 chunks of 16B; swizzle ch ^= (row>>1)&3 -> exactly 2-way (free, m136).
// 4 glds16/thread/K-tile. XCD affinity: block b serves expert e = b&7.

#define STAGE(Ad, Bd, KT) {                                                      \
  glds16(ga[0] + (size_t)(KT) * 32, &Ad[threadIdx.x * 8]);                       \
  glds16(ga[1] + (size_t)(KT) * 32, &Ad[(256 + threadIdx.x) * 8]);               \
  glds16(gb[0] + (size_t)(KT) * 32, &Bd[threadIdx.x * 8]);                       \
  glds16(gb[1] + (size_t)(KT) * 32, &Bd[(256 + threadIdx.x) * 8]);               \
}

#define GEMM_TILE(As, Bs) {                                                      \
  short8 afr[4], bfr[4];                                                         \
  _Pragma("unroll") for (int i = 0; i < 4; ++i) {                                \
    afr[i] = *(const short8*)&As[oa[i]];                                         \
    bfr[i] = *(const short8*)&Bs[ob[i]];                                         \
  }                                                                              \
  _Pragma("unroll") for (int i = 0; i < 4; ++i)                                  \
    _Pragma("unroll") for (int j = 0; j < 4; ++j)                                \
      acc[i][j] = __builtin_amdgcn_mfma_f32_16x16x32_bf16(                       \
          afr[i], bfr[j], acc[i][j], 0, 0, 0);                                   \
}

#define FRAG_OFFSETS {                                                           \
  _Pragma("unroll") for (int i = 0; i < 4; ++i) {                                \
    int Ra = wr * 64 + i * 16 + lr;                                              \
    oa[i] = Ra * 32 + ((lg ^ ((Ra >> 1) & 3)) * 8);                              \
    int Rb = wc * 64 + i * 16 + lr;                                              \
    ob[i] = Rb * 32 + ((lg ^ ((Rb >> 1) & 3)) * 8);                              \
  }                                                                              \
}

// ---------- stage 1: h = gelu(tok_rows @ w1[e] + b1[e]) ----------
__global__ __launch_bounds__(256) void ffn1_k(const u16* __restrict__ tok,
                                              const u16* __restrict__ w1t,
                                              const float* __restrict__ b1,
                                              const int* __restrict__ rlt,
                                              const int* __restrict__ cnt,
                                              u16* __restrict__ h) {
  __shared__ __align__(16) short A0[4096];   // 128x32 bf16
  __shared__ __align__(16) short A1[4096];
  __shared__ __align__(16) short B0[4096];   // 128x32 bf16
  __shared__ __align__(16) short B1[4096];

  int tid = threadIdx.x, w = tid >> 6, l = tid & 63;
  int wr = w >> 1, wc = w & 1;
  int lr = l & 15, lg = l >> 4;
  int oa[4], ob[4];
  FRAG_OFFSETS

  int e = blockIdx.x & 7;
  int rnk = blockIdx.x >> 3;
  int estr = gridDim.x >> 3;
  int m0 = 0;
  #pragma unroll
  for (int i = 0; i < 8; ++i) { int ci = cnt[i]; if (i < e) m0 += ci; }
  int ne = cnt[e];
  int mts = (ne + 127) >> 7;
  int NT_e = mts * (EXPAND / 128);           // mt-tiles x 16 nt

  for (int r = rnk; r < NT_e; r += estr) {
    int mt = r >> 4, nt = r & 15;            // nt-inner: consecutive ranks share A
    int m0g = m0 + mt * 128;
    int mrem = ne - mt * 128;

    const u16* ga[2]; const u16* gb[2];
    #pragma unroll
    for (int c = 0; c < 2; ++c) {
      int flat = c * 256 + tid, rih = flat >> 2;   // 0..127
      int cc = (flat & 3) ^ ((rih >> 1) & 3);      // pre-swizzled source chunk
      int tokid = rlt[m0g + ((rih < mrem) ? rih : 0)];
      ga[c] = tok + (size_t)tokid * HIDDEN + cc * 8;
      int nrow = nt * 128 + rih;
      gb[c] = w1t + (size_t)e * (EXPAND * HIDDEN) + (size_t)nrow * HIDDEN + cc * 8;
    }

    f32x4 acc[4][4] = {};
    STAGE(A0, B0, 0)
    __syncthreads();
    #pragma unroll 1
    for (int it = 0; it < 16; ++it) {              // NK = 32, 2 K-tiles/iter
      STAGE(A1, B1, 2 * it + 1)
      GEMM_TILE(A0, B0)
      __syncthreads();
      if (it < 15) STAGE(A0, B0, 2 * it + 2)
      GEMM_TILE(A1, B1)
      __syncthreads();
    }

    #pragma unroll
    for (int i = 0; i < 4; ++i) {
      #pragma unroll
      for (int rr = 0; rr < 4; ++rr) {
        int row = wr * 64 + i * 16 + lg * 4 + rr;
        if (row >= mrem) continue;
        size_t hrow = (size_t)(m0g + row) * EXPAND;
        #pragma unroll
        for (int j = 0; j < 4; ++j) {
          int col = nt * 128 + wc * 64 + j * 16 + lr;
          float x = acc[i][j][rr] + b1[e * EXPAND + col];
          h[hrow + col] = f2bf(gelu_tanh(x));
        }
      }
    }
  }
}

// ---------- stage 2: obuf[row] = bf16( gate * (h[row] @ w2[e] + b2[e]) ) ----------
__global__ __launch_bounds__(256) void ffn2_k(const u16* __restrict__ h,
                                              const u16* __restrict__ w2t,
                                              const float* __restrict__ b2,
                                              const float* __restrict__ rlg,
                                              const int* __restrict__ cnt,
                                              u16* __restrict__ obuf) {
  __shared__ __align__(16) short A0[4096];
  __shared__ __align__(16) short A1[4096];
  __shared__ __align__(16) short B0[4096];
  __shared__ __align__(16) short B1[4096];

  int tid = threadIdx.x, w = tid >> 6, l = tid & 63;
  int wr = w >> 1, wc = w & 1;
  int lr = l & 15, lg = l >> 4;
  int oa[4], ob[4];
  FRAG_OFFSETS

  int e = blockIdx.x & 7;
  int rnk = blockIdx.x >> 3;
  int estr = gridDim.x >> 3;
  int m0 = 0;
  #pragma unroll
  for (int i = 0; i < 8; ++i) { int ci = cnt[i]; if (i < e) m0 += ci; }
  int ne = cnt[e];
  int mts = (ne + 127) >> 7;
  int NT_e = mts * (HIDDEN / 128);           // mt-tiles x 8 nt

  for (int r = rnk; r < NT_e; r += estr) {
    int mt = r >> 3, nt = r & 7;
    int m0g = m0 + mt * 128;
    int mrem = ne - mt * 128;

    const u16* ga[2]; const u16* gb[2];
    #pragma unroll
    for (int c = 0; c < 2; ++c) {
      int flat = c * 256 + tid, rih = flat >> 2;
      int cc = (flat & 3) ^ ((rih >> 1) & 3);
      int rowg = m0g + ((rih < mrem) ? rih : 0);
      ga[c] = h + (size_t)rowg * EXPAND + cc * 8;
      int nrow = nt * 128 + rih;
      gb[c] = w2t + (size_t)e * (HIDDEN * EXPAND) + (size_t)nrow * EXPAND + cc * 8;
    }

    f32x4 acc[4][4] = {};
    STAGE(A0, B0, 0)
    __syncthreads();
    #pragma unroll 1
    for (int it = 0; it < 32; ++it) {              // NK = 64, 2 K-tiles/iter
      STAGE(A1, B1, 2 * it + 1)
      GEMM_TILE(A0, B0)
      __syncthreads();
      if (it < 31) STAGE(A0, B0, 2 * it + 2)
      GEMM_TILE(A1, B1)
      __syncthreads();
    }

    #pragma unroll
    for (int i = 0; i < 4; ++i) {
      #pragma unroll
      for (int rr = 0; rr < 4; ++rr) {
        int row = wr * 64 + i * 16 + lg * 4 + rr;
        if (row >= mrem) continue;
        float gate = rlg[m0g + row];
        size_t orow = (size_t)(m0g + row) * HIDDEN;
        #pragma unroll
        for (int j = 0; j < 4; ++j) {
          int col = nt * 128 + wc * 64 + j * 16 + lr;
          obuf[orow + col] = f2bf((acc[i][j][rr] + b2[e * HIDDEN + col]) * gate);
        }
      }
    }
  }
}

// ---------- combine: out[t] = obuf[row0(t)] + obuf[row1(t)]  (bf16 in, fp32 out) ----------
__global__ __launch_bounds__(256) void combine_k(const u16* __restrict__ obuf,
                                                 const int* __restrict__ rows2,
                                                 float* __restrict__ out) {
  int t = blockIdx.x, c = threadIdx.x;
  int r0 = rows2[t * 2], r1 = rows2[t * 2 + 1];
  ushort4 a = ((const ushort4*)obuf)[(size_t)r0 * 256 + c];
  ushort4 b = ((const ushort4*)obuf)[(size_t)r1 * 256 + c];
  float4 o;
  o.x = bf2f(a.x) + bf2f(b.x);
  o.y = bf2f(a.y) + bf2f(b.y);
  o.z = bf2f(a.z) + bf2f(b.z);
  o.w = bf2f(a.w) + bf2f(b.w);
  ((float4*)out)[(size_t)t * 256 + c] = o;
}

extern "C" void kernel_launch(void* const* d_in, const int* in_sizes, int n_in,
                              void* d_out, int out_size, void* d_ws, size_t ws_size,
                              hipStream_t stream) {
  const float* tokens   = (const float*)d_in[0];
  const float* router_w = (const float*)d_in[1];
  const float* router_b = (const float*)d_in[2];
  const float* w1       = (const float*)d_in[3];
  const float* b1       = (const float*)d_in[4];
  const float* w2       = (const float*)d_in[5];
  const float* b2       = (const float*)d_in[6];
  float* out = (float*)d_out;

  char* ws = (char*)d_ws;
  u16*   tokb  = (u16*)(ws + TOKB_OFF);
  u16*   w1t   = (u16*)(ws + W1T_OFF);
  u16*   obuf  = (u16*)(ws + OBUF_OFF);
  u16*   w2t   = (u16*)(ws + W2T_OFF);
  u16*   h     = (u16*)(ws + H_OFF);
  int*   rlt   = (int*)(ws + RLT_OFF);
  float* rlg   = (float*)(ws + RLG_OFF);
  int*   cnt   = (int*)(ws + CNT_OFF);
  int*   e01   = (int*)(ws + E01_OFF);
  float* gates = (float*)(ws + GATE_OFF);
  int*   rows2 = (int*)(ws + ROWS2_OFF);

  cvt_transpose_k<<<dim3(EXPAND / 64, HIDDEN / 64, N_EXP), 256, 0, stream>>>(
      w1, w1t, HIDDEN, EXPAND);
  cvt_transpose_k<<<dim3(HIDDEN / 64, EXPAND / 64, N_EXP), 256, 0, stream>>>(
      w2, w2t, EXPAND, HIDDEN);
  logits_k<<<N_TOKENS / 4, 256, 0, stream>>>(tokens, router_w, router_b, tokb, e01, gates);
  order_k<<<1, 1024, 0, stream>>>(e01, gates, cnt, rlt, rlg, rows2);
  ffn1_k<<<1024, 256, 0, stream>>>(tokb, w1t, b1, rlt, cnt, h);
  ffn2_k<<<512, 256, 0, stream>>>(h, w2t, b2, rlg, cnt, obuf);
  combine_k<<<N_TOKENS, 256, 0, stream>>>(obuf, rows2, out);
}

// Round 20
// 202.697 us; speedup vs baseline: 1.0962x; 1.0962x over previous
//
#include <hip/hip_runtime.h>
#include <hip/hip_bf16.h>

typedef unsigned short u16;
typedef __attribute__((ext_vector_type(8))) short short8;
typedef __attribute__((ext_vector_type(4))) float f32x4;

#define N_TOKENS 4096
#define HIDDEN   1024
#define N_EXP    8
#define EXPAND   2048

// ---------- workspace layout (bytes) ----------
#define TOKB_OFF  0ull                   // bf16 tokens      [4096][1024]    8,388,608
#define W1T_OFF   8388608ull             // bf16 w1^T        [8][2048][1024] 33,554,432
#define OBUF_OFF  8388608ull             // bf16 obuf        [8192][1024]    16,777,216 (reuses w1t after ffn1)
#define W2T_OFF   41943040ull            // bf16 w2^T        [8][1024][2048] 33,554,432
#define H_OFF     75497472ull            // bf16 h           [8192][2048]    33,554,432
#define RLT_OFF   109051904ull           // int rowlist_token[8192]
#define RLG_OFF   109084672ull           // float rowlist_gate[8192]
#define CNT_OFF   109117440ull           // int cnt[8]
#define E01_OFF   109117472ull           // int e01[4096][2]
#define GATE_OFF  109183008ull           // float gates[4096][2]
#define ROWS2_OFF 109215776ull           // int rows2[4096][2]

__device__ __forceinline__ u16 f2bf(float f) {
  union { float f; unsigned u; } v; v.f = f;
  unsigned r = v.u + 0x7fffu + ((v.u >> 16) & 1u);   // round-to-nearest-even
  return (u16)(r >> 16);
}

__device__ __forceinline__ float bf2f(u16 b) {
  union { unsigned u; float f; } v; v.u = ((unsigned)b) << 16;
  return v.f;
}

__device__ __forceinline__ void glds16(const void* g, void* l) {
  __builtin_amdgcn_global_load_lds(
      (const __attribute__((address_space(1))) void*)g,
      (__attribute__((address_space(3))) void*)l, 16, 0, 0);
}

__device__ __forceinline__ float gelu_tanh(float x) {
  float u = x * (0.7978845608f + 0.0356774081f * x * x);
  float t = __expf(-2.0f * fabsf(u));
  float th = (1.0f - t) / (1.0f + t);
  th = (u >= 0.0f) ? th : -th;
  return 0.5f * x * (1.0f + th);
}

// ---------- merged fp32 [E][R][C] -> bf16 [E][C][R] for BOTH w1 and w2 ----------
// blocks [0,4096): w1 (R=1024, C=2048); [4096,8192): w2 (R=2048, C=1024).
__global__ __launch_bounds__(256) void cvt_both_k(const float* __restrict__ w1,
                                                  u16* __restrict__ w1t,
                                                  const float* __restrict__ w2,
                                                  u16* __restrict__ w2t) {
  __shared__ u16 t[64][66];
  int x = blockIdx.x;
  const float* in; u16* out; int R, C, cx, ry, e;
  if (x < 4096) {
    e = x >> 9; int rem = x & 511;
    cx = rem & 31; ry = rem >> 5;        // C/64=32, R/64=16
    in = w1; out = w1t; R = HIDDEN; C = EXPAND;
  } else {
    int idx = x - 4096;
    e = idx >> 9; int rem = idx & 511;
    cx = rem & 15; ry = rem >> 4;        // C/64=16, R/64=32
    in = w2; out = w2t; R = EXPAND; C = HIDDEN;
  }
  int c0 = cx * 64, r0 = ry * 64;
  const float* ip = in + (size_t)e * R * C;
  u16* op = out + (size_t)e * R * C;
  int tid = threadIdx.x;
  #pragma unroll
  for (int i = 0; i < 16; ++i) {
    int flat = i * 256 + tid;
    int row = flat >> 6, col = flat & 63;
    t[row][col] = f2bf(ip[(size_t)(r0 + row) * C + c0 + col]);
  }
  __syncthreads();
  #pragma unroll
  for (int i = 0; i < 16; ++i) {
    int flat = i * 256 + tid;
    int orow = flat >> 6, ocol = flat & 63;       // out row = col-index, 128B stores
    op[(size_t)(c0 + orow) * R + r0 + ocol] = t[ocol][orow];
  }
}

// ---------- logits + top-2 + softmax + fused tokens->bf16 (float4 loads) ----------
__global__ __launch_bounds__(256) void logits_k(const float* __restrict__ tokens,
                                                const float* __restrict__ rw,
                                                const float* __restrict__ rb,
                                                u16* __restrict__ tokb,
                                                int* __restrict__ e01,
                                                float* __restrict__ gates) {
  __shared__ float rwl[N_EXP * HIDDEN];
  int tid = threadIdx.x;
  for (int i = tid; i < N_EXP * HIDDEN / 4; i += 256)
    ((float4*)rwl)[i] = ((const float4*)rw)[i];
  __syncthreads();
  int w = tid >> 6, l = tid & 63;
  int t = blockIdx.x * 4 + w;
  const float* tp = tokens + (size_t)t * HIDDEN;
  u16* tb = tokb + (size_t)t * HIDDEN;
  float acc[8] = {0.f,0.f,0.f,0.f,0.f,0.f,0.f,0.f};
  #pragma unroll
  for (int it = 0; it < 4; ++it) {
    int k = it * 256 + l * 4;
    float4 tv = *(const float4*)&tp[k];
    ushort4 o;
    o.x = f2bf(tv.x); o.y = f2bf(tv.y); o.z = f2bf(tv.z); o.w = f2bf(tv.w);
    *(ushort4*)&tb[k] = o;
    #pragma unroll
    for (int e = 0; e < 8; ++e) {
      const float4 rv = *(const float4*)&rwl[e * HIDDEN + k];
      acc[e] += tv.x * rv.x + tv.y * rv.y + tv.z * rv.z + tv.w * rv.w;
    }
  }
  #pragma unroll
  for (int off = 32; off >= 1; off >>= 1) {
    #pragma unroll
    for (int e = 0; e < 8; ++e) acc[e] += __shfl_xor(acc[e], off);
  }
  if (l == 0) {
    float lg[8];
    #pragma unroll
    for (int e = 0; e < 8; ++e) lg[e] = acc[e] + rb[e];
    int b0 = 0; float v0 = lg[0];
    #pragma unroll
    for (int e = 1; e < 8; ++e) if (lg[e] > v0) { v0 = lg[e]; b0 = e; }
    int b1 = -1; float v1 = -3.4e38f;
    #pragma unroll
    for (int e = 0; e < 8; ++e) {
      if (e == b0) continue;
      if (lg[e] > v1) { v1 = lg[e]; b1 = e; }
    }
    float d = expf(v1 - v0);
    float p1 = d / (1.f + d);
    float p0 = 1.f - p1;
    e01[t * 2] = b0;   e01[t * 2 + 1] = b1;
    gates[t * 2] = p0; gates[t * 2 + 1] = p1;
  }
}

// ---------- deterministic stable counting sort by expert (single block) ----------
__global__ __launch_bounds__(1024) void order_k(const int* __restrict__ e01,
                                                const float* __restrict__ gates,
                                                int* __restrict__ cnt,
                                                int* __restrict__ rlt,
                                                float* __restrict__ rlg,
                                                int* __restrict__ rows2) {
  __shared__ int slotbuf[2 * N_TOKENS];
  __shared__ int wcnt[16][N_EXP];
  __shared__ int base_run[N_EXP];
  __shared__ int basep[N_EXP];
  int tid = threadIdx.x, w = tid >> 6, l = tid & 63;
  if (tid < N_EXP) base_run[tid] = 0;
  __syncthreads();
  unsigned long long ltmask = (1ull << l) - 1ull;
  #pragma unroll
  for (int c = 0; c < 8; ++c) {
    int i = c * 1024 + tid;
    int ei = e01[i];
    int myrank = 0;
    #pragma unroll
    for (int e = 0; e < N_EXP; ++e) {
      unsigned long long b = __ballot(ei == e);
      if (l == 0) wcnt[w][e] = __popcll(b);
      if (ei == e) myrank = __popcll(b & ltmask);
    }
    __syncthreads();
    if (tid < N_EXP) {
      int e = tid, off = base_run[e];
      #pragma unroll
      for (int ww = 0; ww < 16; ++ww) {
        int v = wcnt[ww][e]; wcnt[ww][e] = off; off += v;
      }
      base_run[e] = off;
    }
    __syncthreads();
    slotbuf[i] = wcnt[w][ei] + myrank;
    __syncthreads();
  }
  if (tid < N_EXP) cnt[tid] = base_run[tid];
  if (tid == 0) {
    int s = 0;
    for (int e = 0; e < N_EXP; ++e) { basep[e] = s; s += base_run[e]; }
  }
  __syncthreads();
  #pragma unroll
  for (int c = 0; c < 8; ++c) {
    int i = c * 1024 + tid;
    int e = e01[i];
    int row = basep[e] + slotbuf[i];
    rlt[row] = i >> 1;
    rlg[row] = gates[i];
    rows2[i] = row;
  }
}

// ======= R18 winner: 128x64x64 tile; 512 thr / 8 waves (4M x 2N), wave tile 32x32 =======
// Named A0/A1 (16 KB) + B0/B1 (8 KB) = 48 KB -> 3 blocks/CU -> 24 waves/CU (6/SIMD).
// 3 glds16/thread/K-tile. XCD affinity: block b serves expert e = b&7.

#define STAGE(Ad, Bd, KT) {                                                      \
  glds16(ga[0] + (size_t)(KT) * 64, &Ad[threadIdx.x * 8]);                       \
  glds16(ga[1] + (size_t)(KT) * 64, &Ad[(512 + threadIdx.x) * 8]);               \
  glds16(gb0   + (size_t)(KT) * 64, &Bd[threadIdx.x * 8]);                       \
}

#define GEMM_TILE(As, Bs) {                                                      \
  _Pragma("unroll") for (int kk = 0; kk < 2; ++kk) {                             \
    short8 afr[2], bfr[2];                                                       \
    _Pragma("unroll") for (int i = 0; i < 2; ++i) {                              \
      afr[i] = *(const short8*)&As[oa[kk][i]];                                   \
      bfr[i] = *(const short8*)&Bs[ob[kk][i]];                                   \
    }                                                                            \
    _Pragma("unroll") for (int i = 0; i < 2; ++i)                                \
      _Pragma("unroll") for (int j = 0; j < 2; ++j)                              \
        acc[i][j] = __builtin_amdgcn_mfma_f32_16x16x32_bf16(                     \
            afr[i], bfr[j], acc[i][j], 0, 0, 0);                                 \
  }                                                                              \
}

#define FRAG_OFFSETS {                                                           \
  _Pragma("unroll") for (int kk = 0; kk < 2; ++kk) {                             \
    int cc = kk * 4 + lg;                                                        \
    _Pragma("unroll") for (int i = 0; i < 2; ++i) {                              \
      int Ra = wr * 32 + i * 16 + lr;                                            \
      oa[kk][i] = Ra * 64 + (cc ^ (Ra & 7)) * 8;                                 \
      int Rb = wc * 32 + i * 16 + lr;                                            \
      ob[kk][i] = Rb * 64 + (cc ^ (Rb & 7)) * 8;                                 \
    }                                                                            \
  }                                                                              \
}

// ---------- stage 1: h = gelu(tok_rows @ w1[e] + b1[e]) ----------
__global__ __launch_bounds__(512) void ffn1_k(const u16* __restrict__ tok,
                                              const u16* __restrict__ w1t,
                                              const float* __restrict__ b1,
                                              const int* __restrict__ rlt,
                                              const int* __restrict__ cnt,
                                              u16* __restrict__ h) {
  __shared__ __align__(16) short A0[8192];   // 128x64 bf16
  __shared__ __align__(16) short A1[8192];
  __shared__ __align__(16) short B0[4096];   // 64x64 bf16
  __shared__ __align__(16) short B1[4096];

  int tid = threadIdx.x, w = tid >> 6, l = tid & 63;
  int wr = w >> 1, wc = w & 1;               // 4M x 2N
  int lr = l & 15, lg = l >> 4;
  int oa[2][2], ob[2][2];
  FRAG_OFFSETS

  int e = blockIdx.x & 7;
  int rnk = blockIdx.x >> 3;
  int estr = gridDim.x >> 3;
  int m0 = 0;
  #pragma unroll
  for (int i = 0; i < 8; ++i) { int ci = cnt[i]; if (i < e) m0 += ci; }
  int ne = cnt[e];
  int mts = (ne + 127) >> 7;
  int NT_e = mts * (EXPAND / 64);            // mt-tiles x 32 nt

  for (int r = rnk; r < NT_e; r += estr) {
    int mt = r >> 5, nt = r & 31;            // nt-inner: consecutive ranks share A
    int m0g = m0 + mt * 128;
    int mrem = ne - mt * 128;

    const u16* ga[2]; const u16* gb0;
    #pragma unroll
    for (int c = 0; c < 2; ++c) {
      int flat = c * 512 + tid, rih = flat >> 3;   // 0..127
      int ch = (flat & 7) ^ (rih & 7);
      int tokid = rlt[m0g + ((rih < mrem) ? rih : 0)];
      ga[c] = tok + (size_t)tokid * HIDDEN + ch * 8;
    }
    {
      int rih = tid >> 3;                          // 0..63
      int ch = (tid & 7) ^ (rih & 7);
      int nrow = nt * 64 + rih;
      gb0 = w1t + (size_t)e * (EXPAND * HIDDEN) + (size_t)nrow * HIDDEN + ch * 8;
    }

    f32x4 acc[2][2] = {};
    STAGE(A0, B0, 0)
    __syncthreads();
    #pragma unroll 1
    for (int it = 0; it < 8; ++it) {               // NK = 16, 2 K-tiles/iter
      STAGE(A1, B1, 2 * it + 1)
      GEMM_TILE(A0, B0)
      __syncthreads();
      if (it < 7) STAGE(A0, B0, 2 * it + 2)
      GEMM_TILE(A1, B1)
      __syncthreads();
    }

    #pragma unroll
    for (int i = 0; i < 2; ++i) {
      #pragma unroll
      for (int rr = 0; rr < 4; ++rr) {
        int row = wr * 32 + i * 16 + lg * 4 + rr;
        if (row >= mrem) continue;
        size_t hrow = (size_t)(m0g + row) * EXPAND;
        #pragma unroll
        for (int j = 0; j < 2; ++j) {
          int col = nt * 64 + wc * 32 + j * 16 + lr;
          float x = acc[i][j][rr] + b1[e * EXPAND + col];
          h[hrow + col] = f2bf(gelu_tanh(x));
        }
      }
    }
  }
}

// ---------- stage 2: obuf[row] = bf16( gate * (h[row] @ w2[e] + b2[e]) ) ----------
__global__ __launch_bounds__(512) void ffn2_k(const u16* __restrict__ h,
                                              const u16* __restrict__ w2t,
                                              const float* __restrict__ b2,
                                              const float* __restrict__ rlg,
                                              const int* __restrict__ cnt,
                                              u16* __restrict__ obuf) {
  __shared__ __align__(16) short A0[8192];
  __shared__ __align__(16) short A1[8192];
  __shared__ __align__(16) short B0[4096];
  __shared__ __align__(16) short B1[4096];

  int tid = threadIdx.x, w = tid >> 6, l = tid & 63;
  int wr = w >> 1, wc = w & 1;
  int lr = l & 15, lg = l >> 4;
  int oa[2][2], ob[2][2];
  FRAG_OFFSETS

  int e = blockIdx.x & 7;
  int rnk = blockIdx.x >> 3;
  int estr = gridDim.x >> 3;
  int m0 = 0;
  #pragma unroll
  for (int i = 0; i < 8; ++i) { int ci = cnt[i]; if (i < e) m0 += ci; }
  int ne = cnt[e];
  int mts = (ne + 127) >> 7;
  int NT_e = mts * (HIDDEN / 64);            // mt-tiles x 16 nt

  for (int r = rnk; r < NT_e; r += estr) {
    int mt = r >> 4, nt = r & 15;
    int m0g = m0 + mt * 128;
    int mrem = ne - mt * 128;

    const u16* ga[2]; const u16* gb0;
    #pragma unroll
    for (int c = 0; c < 2; ++c) {
      int flat = c * 512 + tid, rih = flat >> 3;
      int ch = (flat & 7) ^ (rih & 7);
      int rowg = m0g + ((rih < mrem) ? rih : 0);
      ga[c] = h + (size_t)rowg * EXPAND + ch * 8;
    }
    {
      int rih = tid >> 3;
      int ch = (tid & 7) ^ (rih & 7);
      int nrow = nt * 64 + rih;
      gb0 = w2t + (size_t)e * (HIDDEN * EXPAND) + (size_t)nrow * EXPAND + ch * 8;
    }

    f32x4 acc[2][2] = {};
    STAGE(A0, B0, 0)
    __syncthreads();
    #pragma unroll 1
    for (int it = 0; it < 16; ++it) {              // NK = 32, 2 K-tiles/iter
      STAGE(A1, B1, 2 * it + 1)
      GEMM_TILE(A0, B0)
      __syncthreads();
      if (it < 15) STAGE(A0, B0, 2 * it + 2)
      GEMM_TILE(A1, B1)
      __syncthreads();
    }

    #pragma unroll
    for (int i = 0; i < 2; ++i) {
      #pragma unroll
      for (int rr = 0; rr < 4; ++rr) {
        int row = wr * 32 + i * 16 + lg * 4 + rr;
        if (row >= mrem) continue;
        float gate = rlg[m0g + row];
        size_t orow = (size_t)(m0g + row) * HIDDEN;
        #pragma unroll
        for (int j = 0; j < 2; ++j) {
          int col = nt * 64 + wc * 32 + j * 16 + lr;
          obuf[orow + col] = f2bf((acc[i][j][rr] + b2[e * HIDDEN + col]) * gate);
        }
      }
    }
  }
}

// ---------- combine: out[t] = obuf[row0(t)] + obuf[row1(t)]  (bf16 in, fp32 out) ----------
__global__ __launch_bounds__(256) void combine_k(const u16* __restrict__ obuf,
                                                 const int* __restrict__ rows2,
                                                 float* __restrict__ out) {
  int t = blockIdx.x, c = threadIdx.x;
  int r0 = rows2[t * 2], r1 = rows2[t * 2 + 1];
  ushort4 a = ((const ushort4*)obuf)[(size_t)r0 * 256 + c];
  ushort4 b = ((const ushort4*)obuf)[(size_t)r1 * 256 + c];
  float4 o;
  o.x = bf2f(a.x) + bf2f(b.x);
  o.y = bf2f(a.y) + bf2f(b.y);
  o.z = bf2f(a.z) + bf2f(b.z);
  o.w = bf2f(a.w) + bf2f(b.w);
  ((float4*)out)[(size_t)t * 256 + c] = o;
}

extern "C" void kernel_launch(void* const* d_in, const int* in_sizes, int n_in,
                              void* d_out, int out_size, void* d_ws, size_t ws_size,
                              hipStream_t stream) {
  const float* tokens   = (const float*)d_in[0];
  const float* router_w = (const float*)d_in[1];
  const float* router_b = (const float*)d_in[2];
  const float* w1       = (const float*)d_in[3];
  const float* b1       = (const float*)d_in[4];
  const float* w2       = (const float*)d_in[5];
  const float* b2       = (const float*)d_in[6];
  float* out = (float*)d_out;

  char* ws = (char*)d_ws;
  u16*   tokb  = (u16*)(ws + TOKB_OFF);
  u16*   w1t   = (u16*)(ws + W1T_OFF);
  u16*   obuf  = (u16*)(ws + OBUF_OFF);
  u16*   w2t   = (u16*)(ws + W2T_OFF);
  u16*   h     = (u16*)(ws + H_OFF);
  int*   rlt   = (int*)(ws + RLT_OFF);
  float* rlg   = (float*)(ws + RLG_OFF);
  int*   cnt   = (int*)(ws + CNT_OFF);
  int*   e01   = (int*)(ws + E01_OFF);
  float* gates = (float*)(ws + GATE_OFF);
  int*   rows2 = (int*)(ws + ROWS2_OFF);

  cvt_both_k<<<8192, 256, 0, stream>>>(w1, w1t, w2, w2t);
  logits_k<<<N_TOKENS / 4, 256, 0, stream>>>(tokens, router_w, router_b, tokb, e01, gates);
  order_k<<<1, 1024, 0, stream>>>(e01, gates, cnt, rlt, rlg, rows2);
  ffn1_k<<<2048, 512, 0, stream>>>(tokb, w1t, b1, rlt, cnt, h);
  ffn2_k<<<1024, 512, 0, stream>>>(h, w2t, b2, rlg, cnt, obuf);
  combine_k<<<N_TOKENS, 256, 0, stream>>>(obuf, rows2, out);
}

// Round 21
// 198.183 us; speedup vs baseline: 1.1212x; 1.0228x over previous
//
#include <hip/hip_runtime.h>
#include <hip/hip_bf16.h>

typedef unsigned short u16;
typedef __attribute__((ext_vector_type(8))) short short8;
typedef __attribute__((ext_vector_type(4))) float f32x4;

#define N_TOKENS 4096
#define HIDDEN   1024
#define N_EXP    8
#define EXPAND   2048

// ---------- workspace layout (bytes) ----------
#define TOKB_OFF  0ull                   // bf16 tokens      [4096][1024]    8,388,608
#define W1T_OFF   8388608ull             // bf16 w1^T        [8][2048][1024] 33,554,432
#define OBUF_OFF  8388608ull             // bf16 obuf        [8192][1024]    16,777,216 (reuses w1t after ffn1)
#define W2T_OFF   41943040ull            // bf16 w2^T        [8][1024][2048] 33,554,432
#define H_OFF     75497472ull            // bf16 h           [8192][2048]    33,554,432
#define RLT_OFF   109051904ull           // int rowlist_token[8192]
#define RLG_OFF   109084672ull           // float rowlist_gate[8192]
#define CNT_OFF   109117440ull           // int cnt[8]
#define E01_OFF   109117472ull           // int e01[4096][2]
#define GATE_OFF  109183008ull           // float gates[4096][2]
#define ROWS2_OFF 109215776ull           // int rows2[4096][2]

__device__ __forceinline__ u16 f2bf(float f) {
  union { float f; unsigned u; } v; v.f = f;
  unsigned r = v.u + 0x7fffu + ((v.u >> 16) & 1u);   // round-to-nearest-even
  return (u16)(r >> 16);
}

__device__ __forceinline__ float bf2f(u16 b) {
  union { unsigned u; float f; } v; v.u = ((unsigned)b) << 16;
  return v.f;
}

__device__ __forceinline__ void glds16(const void* g, void* l) {
  __builtin_amdgcn_global_load_lds(
      (const __attribute__((address_space(1))) void*)g,
      (__attribute__((address_space(3))) void*)l, 16, 0, 0);
}

__device__ __forceinline__ float gelu_tanh(float x) {
  float u = x * (0.7978845608f + 0.0356774081f * x * x);
  float t = __expf(-2.0f * fabsf(u));
  float th = (1.0f - t) / (1.0f + t);
  th = (u >= 0.0f) ? th : -th;
  return 0.5f * x * (1.0f + th);
}

// ---------- merged prep: logits (blocks [0,1024)) + weight transpose ([1024,9216)) ----------
// Independent work items fused into one launch so the router GEMV hides under the
// BW-bound weight transpose instead of serializing after it.
__global__ __launch_bounds__(256) void prep_k(const float* __restrict__ w1,
                                              u16* __restrict__ w1t,
                                              const float* __restrict__ w2,
                                              u16* __restrict__ w2t,
                                              const float* __restrict__ tokens,
                                              const float* __restrict__ rw,
                                              const float* __restrict__ rb,
                                              u16* __restrict__ tokb,
                                              int* __restrict__ e01,
                                              float* __restrict__ gates) {
  __shared__ __align__(16) char smem[32768];
  int x = blockIdx.x;
  int tid = threadIdx.x;

  if (x >= 1024) {
    // ---- transpose tile: idx in [0, 8192) ----
    u16 (*t)[66] = (u16 (*)[66])smem;
    int idx = x - 1024;
    const float* in; u16* out; int R, C, cx, ry, e;
    if (idx < 4096) {
      e = idx >> 9; int rem = idx & 511;
      cx = rem & 31; ry = rem >> 5;        // w1: C/64=32, R/64=16
      in = w1; out = w1t; R = HIDDEN; C = EXPAND;
    } else {
      int id2 = idx - 4096;
      e = id2 >> 9; int rem = id2 & 511;
      cx = rem & 15; ry = rem >> 4;        // w2: C/64=16, R/64=32
      in = w2; out = w2t; R = EXPAND; C = HIDDEN;
    }
    int c0 = cx * 64, r0 = ry * 64;
    const float* ip = in + (size_t)e * R * C;
    u16* op = out + (size_t)e * R * C;
    #pragma unroll
    for (int i = 0; i < 16; ++i) {
      int flat = i * 256 + tid;
      int row = flat >> 6, col = flat & 63;
      t[row][col] = f2bf(ip[(size_t)(r0 + row) * C + c0 + col]);
    }
    __syncthreads();
    #pragma unroll
    for (int i = 0; i < 16; ++i) {
      int flat = i * 256 + tid;
      int orow = flat >> 6, ocol = flat & 63;     // out row = col-index, 128B stores
      op[(size_t)(c0 + orow) * R + r0 + ocol] = t[ocol][orow];
    }
    return;
  }

  // ---- logits: 4 tokens per block ----
  float* rwl = (float*)smem;
  for (int i = tid; i < N_EXP * HIDDEN / 4; i += 256)
    ((float4*)rwl)[i] = ((const float4*)rw)[i];
  __syncthreads();
  int w = tid >> 6, l = tid & 63;
  int t = x * 4 + w;
  const float* tp = tokens + (size_t)t * HIDDEN;
  u16* tb = tokb + (size_t)t * HIDDEN;
  float acc[8] = {0.f,0.f,0.f,0.f,0.f,0.f,0.f,0.f};
  #pragma unroll
  for (int it = 0; it < 4; ++it) {
    int k = it * 256 + l * 4;
    float4 tv = *(const float4*)&tp[k];
    ushort4 o;
    o.x = f2bf(tv.x); o.y = f2bf(tv.y); o.z = f2bf(tv.z); o.w = f2bf(tv.w);
    *(ushort4*)&tb[k] = o;
    #pragma unroll
    for (int e = 0; e < 8; ++e) {
      const float4 rv = *(const float4*)&rwl[e * HIDDEN + k];
      acc[e] += tv.x * rv.x + tv.y * rv.y + tv.z * rv.z + tv.w * rv.w;
    }
  }
  #pragma unroll
  for (int off = 32; off >= 1; off >>= 1) {
    #pragma unroll
    for (int e = 0; e < 8; ++e) acc[e] += __shfl_xor(acc[e], off);
  }
  if (l == 0) {
    float lg[8];
    #pragma unroll
    for (int e = 0; e < 8; ++e) lg[e] = acc[e] + rb[e];
    int b0 = 0; float v0 = lg[0];
    #pragma unroll
    for (int e = 1; e < 8; ++e) if (lg[e] > v0) { v0 = lg[e]; b0 = e; }
    int b1 = -1; float v1 = -3.4e38f;
    #pragma unroll
    for (int e = 0; e < 8; ++e) {
      if (e == b0) continue;
      if (lg[e] > v1) { v1 = lg[e]; b1 = e; }
    }
    float d = expf(v1 - v0);
    float p1 = d / (1.f + d);
    float p0 = 1.f - p1;
    e01[t * 2] = b0;   e01[t * 2 + 1] = b1;
    gates[t * 2] = p0; gates[t * 2 + 1] = p1;
  }
}

// ---------- deterministic stable counting sort by expert (single block) ----------
__global__ __launch_bounds__(1024) void order_k(const int* __restrict__ e01,
                                                const float* __restrict__ gates,
                                                int* __restrict__ cnt,
                                                int* __restrict__ rlt,
                                                float* __restrict__ rlg,
                                                int* __restrict__ rows2) {
  __shared__ int slotbuf[2 * N_TOKENS];
  __shared__ int wcnt[16][N_EXP];
  __shared__ int base_run[N_EXP];
  __shared__ int basep[N_EXP];
  int tid = threadIdx.x, w = tid >> 6, l = tid & 63;
  if (tid < N_EXP) base_run[tid] = 0;
  __syncthreads();
  unsigned long long ltmask = (1ull << l) - 1ull;
  #pragma unroll
  for (int c = 0; c < 8; ++c) {
    int i = c * 1024 + tid;
    int ei = e01[i];
    int myrank = 0;
    #pragma unroll
    for (int e = 0; e < N_EXP; ++e) {
      unsigned long long b = __ballot(ei == e);
      if (l == 0) wcnt[w][e] = __popcll(b);
      if (ei == e) myrank = __popcll(b & ltmask);
    }
    __syncthreads();
    if (tid < N_EXP) {
      int e = tid, off = base_run[e];
      #pragma unroll
      for (int ww = 0; ww < 16; ++ww) {
        int v = wcnt[ww][e]; wcnt[ww][e] = off; off += v;
      }
      base_run[e] = off;
    }
    __syncthreads();
    slotbuf[i] = wcnt[w][ei] + myrank;
    __syncthreads();
  }
  if (tid < N_EXP) cnt[tid] = base_run[tid];
  if (tid == 0) {
    int s = 0;
    for (int e = 0; e < N_EXP; ++e) { basep[e] = s; s += base_run[e]; }
  }
  __syncthreads();
  #pragma unroll
  for (int c = 0; c < 8; ++c) {
    int i = c * 1024 + tid;
    int e = e01[i];
    int row = basep[e] + slotbuf[i];
    rlt[row] = i >> 1;
    rlg[row] = gates[i];
    rows2[i] = row;
  }
}

// ======= R18/R20 winner: 128x64x64 tile; 512 thr / 8 waves (4M x 2N), wave tile 32x32 =======
// Named A0/A1 (16 KB) + B0/B1 (8 KB) = 48 KB -> 3 blocks/CU -> 24 waves/CU (6/SIMD).
// 3 glds16/thread/K-tile. XCD affinity: block b serves expert e = b&7.

#define STAGE(Ad, Bd, KT) {                                                      \
  glds16(ga[0] + (size_t)(KT) * 64, &Ad[threadIdx.x * 8]);                       \
  glds16(ga[1] + (size_t)(KT) * 64, &Ad[(512 + threadIdx.x) * 8]);               \
  glds16(gb0   + (size_t)(KT) * 64, &Bd[threadIdx.x * 8]);                       \
}

#define GEMM_TILE(As, Bs) {                                                      \
  _Pragma("unroll") for (int kk = 0; kk < 2; ++kk) {                             \
    short8 afr[2], bfr[2];                                                       \
    _Pragma("unroll") for (int i = 0; i < 2; ++i) {                              \
      afr[i] = *(const short8*)&As[oa[kk][i]];                                   \
      bfr[i] = *(const short8*)&Bs[ob[kk][i]];                                   \
    }                                                                            \
    _Pragma("unroll") for (int i = 0; i < 2; ++i)                                \
      _Pragma("unroll") for (int j = 0; j < 2; ++j)                              \
        acc[i][j] = __builtin_amdgcn_mfma_f32_16x16x32_bf16(                     \
            afr[i], bfr[j], acc[i][j], 0, 0, 0);                                 \
  }                                                                              \
}

#define FRAG_OFFSETS {                                                           \
  _Pragma("unroll") for (int kk = 0; kk < 2; ++kk) {                             \
    int cc = kk * 4 + lg;                                                        \
    _Pragma("unroll") for (int i = 0; i < 2; ++i) {                              \
      int Ra = wr * 32 + i * 16 + lr;                                            \
      oa[kk][i] = Ra * 64 + (cc ^ (Ra & 7)) * 8;                                 \
      int Rb = wc * 32 + i * 16 + lr;                                            \
      ob[kk][i] = Rb * 64 + (cc ^ (Rb & 7)) * 8;                                 \
    }                                                                            \
  }                                                                              \
}

// ---------- stage 1: h = gelu(tok_rows @ w1[e] + b1[e]) ----------
__global__ __launch_bounds__(512) void ffn1_k(const u16* __restrict__ tok,
                                              const u16* __restrict__ w1t,
                                              const float* __restrict__ b1,
                                              const int* __restrict__ rlt,
                                              const int* __restrict__ cnt,
                                              u16* __restrict__ h) {
  __shared__ __align__(16) short A0[8192];   // 128x64 bf16
  __shared__ __align__(16) short A1[8192];
  __shared__ __align__(16) short B0[4096];   // 64x64 bf16
  __shared__ __align__(16) short B1[4096];

  int tid = threadIdx.x, w = tid >> 6, l = tid & 63;
  int wr = w >> 1, wc = w & 1;               // 4M x 2N
  int lr = l & 15, lg = l >> 4;
  int oa[2][2], ob[2][2];
  FRAG_OFFSETS

  int e = blockIdx.x & 7;
  int rnk = blockIdx.x >> 3;
  int estr = gridDim.x >> 3;
  int m0 = 0;
  #pragma unroll
  for (int i = 0; i < 8; ++i) { int ci = cnt[i]; if (i < e) m0 += ci; }
  int ne = cnt[e];
  int mts = (ne + 127) >> 7;
  int NT_e = mts * (EXPAND / 64);            // mt-tiles x 32 nt

  for (int r = rnk; r < NT_e; r += estr) {
    int mt = r >> 5, nt = r & 31;            // nt-inner: consecutive ranks share A
    int m0g = m0 + mt * 128;
    int mrem = ne - mt * 128;

    const u16* ga[2]; const u16* gb0;
    #pragma unroll
    for (int c = 0; c < 2; ++c) {
      int flat = c * 512 + tid, rih = flat >> 3;   // 0..127
      int ch = (flat & 7) ^ (rih & 7);
      int tokid = rlt[m0g + ((rih < mrem) ? rih : 0)];
      ga[c] = tok + (size_t)tokid * HIDDEN + ch * 8;
    }
    {
      int rih = tid >> 3;                          // 0..63
      int ch = (tid & 7) ^ (rih & 7);
      int nrow = nt * 64 + rih;
      gb0 = w1t + (size_t)e * (EXPAND * HIDDEN) + (size_t)nrow * HIDDEN + ch * 8;
    }

    f32x4 acc[2][2] = {};
    STAGE(A0, B0, 0)
    __syncthreads();
    #pragma unroll 1
    for (int it = 0; it < 8; ++it) {               // NK = 16, 2 K-tiles/iter
      STAGE(A1, B1, 2 * it + 1)
      GEMM_TILE(A0, B0)
      __syncthreads();
      if (it < 7) STAGE(A0, B0, 2 * it + 2)
      GEMM_TILE(A1, B1)
      __syncthreads();
    }

    #pragma unroll
    for (int i = 0; i < 2; ++i) {
      #pragma unroll
      for (int rr = 0; rr < 4; ++rr) {
        int row = wr * 32 + i * 16 + lg * 4 + rr;
        if (row >= mrem) continue;
        size_t hrow = (size_t)(m0g + row) * EXPAND;
        #pragma unroll
        for (int j = 0; j < 2; ++j) {
          int col = nt * 64 + wc * 32 + j * 16 + lr;
          float x = acc[i][j][rr] + b1[e * EXPAND + col];
          h[hrow + col] = f2bf(gelu_tanh(x));
        }
      }
    }
  }
}

// ---------- stage 2: obuf[row] = bf16( gate * (h[row] @ w2[e] + b2[e]) ) ----------
__global__ __launch_bounds__(512) void ffn2_k(const u16* __restrict__ h,
                                              const u16* __restrict__ w2t,
                                              const float* __restrict__ b2,
                                              const float* __restrict__ rlg,
                                              const int* __restrict__ cnt,
                                              u16* __restrict__ obuf) {
  __shared__ __align__(16) short A0[8192];
  __shared__ __align__(16) short A1[8192];
  __shared__ __align__(16) short B0[4096];
  __shared__ __align__(16) short B1[4096];

  int tid = threadIdx.x, w = tid >> 6, l = tid & 63;
  int wr = w >> 1, wc = w & 1;
  int lr = l & 15, lg = l >> 4;
  int oa[2][2], ob[2][2];
  FRAG_OFFSETS

  int e = blockIdx.x & 7;
  int rnk = blockIdx.x >> 3;
  int estr = gridDim.x >> 3;
  int m0 = 0;
  #pragma unroll
  for (int i = 0; i < 8; ++i) { int ci = cnt[i]; if (i < e) m0 += ci; }
  int ne = cnt[e];
  int mts = (ne + 127) >> 7;
  int NT_e = mts * (HIDDEN / 64);            // mt-tiles x 16 nt

  for (int r = rnk; r < NT_e; r += estr) {
    int mt = r >> 4, nt = r & 15;
    int m0g = m0 + mt * 128;
    int mrem = ne - mt * 128;

    const u16* ga[2]; const u16* gb0;
    #pragma unroll
    for (int c = 0; c < 2; ++c) {
      int flat = c * 512 + tid, rih = flat >> 3;
      int ch = (flat & 7) ^ (rih & 7);
      int rowg = m0g + ((rih < mrem) ? rih : 0);
      ga[c] = h + (size_t)rowg * EXPAND + ch * 8;
    }
    {
      int rih = tid >> 3;
      int ch = (tid & 7) ^ (rih & 7);
      int nrow = nt * 64 + rih;
      gb0 = w2t + (size_t)e * (HIDDEN * EXPAND) + (size_t)nrow * EXPAND + ch * 8;
    }

    f32x4 acc[2][2] = {};
    STAGE(A0, B0, 0)
    __syncthreads();
    #pragma unroll 1
    for (int it = 0; it < 16; ++it) {              // NK = 32, 2 K-tiles/iter
      STAGE(A1, B1, 2 * it + 1)
      GEMM_TILE(A0, B0)
      __syncthreads();
      if (it < 15) STAGE(A0, B0, 2 * it + 2)
      GEMM_TILE(A1, B1)
      __syncthreads();
    }

    #pragma unroll
    for (int i = 0; i < 2; ++i) {
      #pragma unroll
      for (int rr = 0; rr < 4; ++rr) {
        int row = wr * 32 + i * 16 + lg * 4 + rr;
        if (row >= mrem) continue;
        float gate = rlg[m0g + row];
        size_t orow = (size_t)(m0g + row) * HIDDEN;
        #pragma unroll
        for (int j = 0; j < 2; ++j) {
          int col = nt * 64 + wc * 32 + j * 16 + lr;
          obuf[orow + col] = f2bf((acc[i][j][rr] + b2[e * HIDDEN + col]) * gate);
        }
      }
    }
  }
}

// ---------- combine: out[t] = obuf[row0(t)] + obuf[row1(t)]  (bf16 in, fp32 out) ----------
__global__ __launch_bounds__(256) void combine_k(const u16* __restrict__ obuf,
                                                 const int* __restrict__ rows2,
                                                 float* __restrict__ out) {
  int t = blockIdx.x, c = threadIdx.x;
  int r0 = rows2[t * 2], r1 = rows2[t * 2 + 1];
  ushort4 a = ((const ushort4*)obuf)[(size_t)r0 * 256 + c];
  ushort4 b = ((const ushort4*)obuf)[(size_t)r1 * 256 + c];
  float4 o;
  o.x = bf2f(a.x) + bf2f(b.x);
  o.y = bf2f(a.y) + bf2f(b.y);
  o.z = bf2f(a.z) + bf2f(b.z);
  o.w = bf2f(a.w) + bf2f(b.w);
  ((float4*)out)[(size_t)t * 256 + c] = o;
}

extern "C" void kernel_launch(void* const* d_in, const int* in_sizes, int n_in,
                              void* d_out, int out_size, void* d_ws, size_t ws_size,
                              hipStream_t stream) {
  const float* tokens   = (const float*)d_in[0];
  const float* router_w = (const float*)d_in[1];
  const float* router_b = (const float*)d_in[2];
  const float* w1       = (const float*)d_in[3];
  const float* b1       = (const float*)d_in[4];
  const float* w2       = (const float*)d_in[5];
  const float* b2       = (const float*)d_in[6];
  float* out = (float*)d_out;

  char* ws = (char*)d_ws;
  u16*   tokb  = (u16*)(ws + TOKB_OFF);
  u16*   w1t   = (u16*)(ws + W1T_OFF);
  u16*   obuf  = (u16*)(ws + OBUF_OFF);
  u16*   w2t   = (u16*)(ws + W2T_OFF);
  u16*   h     = (u16*)(ws + H_OFF);
  int*   rlt   = (int*)(ws + RLT_OFF);
  float* rlg   = (float*)(ws + RLG_OFF);
  int*   cnt   = (int*)(ws + CNT_OFF);
  int*   e01   = (int*)(ws + E01_OFF);
  float* gates = (float*)(ws + GATE_OFF);
  int*   rows2 = (int*)(ws + ROWS2_OFF);

  prep_k<<<9216, 256, 0, stream>>>(w1, w1t, w2, w2t,
                                   tokens, router_w, router_b, tokb, e01, gates);
  order_k<<<1, 1024, 0, stream>>>(e01, gates, cnt, rlt, rlg, rows2);
  ffn1_k<<<2048, 512, 0, stream>>>(tokb, w1t, b1, rlt, cnt, h);
  ffn2_k<<<1024, 512, 0, stream>>>(h, w2t, b2, rlg, cnt, obuf);
  combine_k<<<N_TOKENS, 256, 0, stream>>>(obuf, rows2, out);
}

// Round 22
// 193.687 us; speedup vs baseline: 1.1472x; 1.0232x over previous
//
#include <hip/hip_runtime.h>
#include <hip/hip_bf16.h>

typedef unsigned short u16;
typedef __attribute__((ext_vector_type(8))) short short8;
typedef __attribute__((ext_vector_type(4))) float f32x4;

#define N_TOKENS 4096
#define HIDDEN   1024
#define N_EXP    8
#define EXPAND   2048

// ---------- workspace layout (bytes) ----------
#define TOKB_OFF  0ull                   // bf16 tokens      [4096][1024]    8,388,608
#define W1T_OFF   8388608ull             // bf16 w1^T        [8][2048][1024] 33,554,432
#define OBUF_OFF  8388608ull             // bf16 obuf        [8192][1024]    16,777,216 (reuses w1t after ffn1)
#define W2T_OFF   41943040ull            // bf16 w2^T        [8][1024][2048] 33,554,432
#define H_OFF     75497472ull            // bf16 h           [8192][2048]    33,554,432
#define RLT_OFF   109051904ull           // int rowlist_token[8192]
#define RLG_OFF   109084672ull           // float rowlist_gate[8192]
#define CNT_OFF   109117440ull           // int cnt[8]
#define E01_OFF   109117472ull           // int e01[4096][2]
#define GATE_OFF  109183008ull           // float gates[4096][2]
#define ROWS2_OFF 109215776ull           // int rows2[4096][2]
#define BCNT_OFF  109248544ull           // int bcnt[8][32]
#define OBASE_OFF 109249568ull           // int obase[8][32]

__device__ __forceinline__ u16 f2bf(float f) {
  union { float f; unsigned u; } v; v.f = f;
  unsigned r = v.u + 0x7fffu + ((v.u >> 16) & 1u);   // round-to-nearest-even
  return (u16)(r >> 16);
}

__device__ __forceinline__ float bf2f(u16 b) {
  union { unsigned u; float f; } v; v.u = ((unsigned)b) << 16;
  return v.f;
}

__device__ __forceinline__ void glds16(const void* g, void* l) {
  __builtin_amdgcn_global_load_lds(
      (const __attribute__((address_space(1))) void*)g,
      (__attribute__((address_space(3))) void*)l, 16, 0, 0);
}

__device__ __forceinline__ float gelu_tanh(float x) {
  float u = x * (0.7978845608f + 0.0356774081f * x * x);
  float t = __expf(-2.0f * fabsf(u));
  float th = (1.0f - t) / (1.0f + t);
  th = (u >= 0.0f) ? th : -th;
  return 0.5f * x * (1.0f + th);
}

// ---------- merged prep: logits (blocks [0,1024)) + weight transpose ([1024,9216)) ----------
__global__ __launch_bounds__(256) void prep_k(const float* __restrict__ w1,
                                              u16* __restrict__ w1t,
                                              const float* __restrict__ w2,
                                              u16* __restrict__ w2t,
                                              const float* __restrict__ tokens,
                                              const float* __restrict__ rw,
                                              const float* __restrict__ rb,
                                              u16* __restrict__ tokb,
                                              int* __restrict__ e01,
                                              float* __restrict__ gates) {
  __shared__ __align__(16) char smem[32768];
  int x = blockIdx.x;
  int tid = threadIdx.x;

  if (x >= 1024) {
    // ---- transpose tile: idx in [0, 8192) ----
    u16 (*t)[66] = (u16 (*)[66])smem;
    int idx = x - 1024;
    const float* in; u16* out; int R, C, cx, ry, e;
    if (idx < 4096) {
      e = idx >> 9; int rem = idx & 511;
      cx = rem & 31; ry = rem >> 5;        // w1: C/64=32, R/64=16
      in = w1; out = w1t; R = HIDDEN; C = EXPAND;
    } else {
      int id2 = idx - 4096;
      e = id2 >> 9; int rem = id2 & 511;
      cx = rem & 15; ry = rem >> 4;        // w2: C/64=16, R/64=32
      in = w2; out = w2t; R = EXPAND; C = HIDDEN;
    }
    int c0 = cx * 64, r0 = ry * 64;
    const float* ip = in + (size_t)e * R * C;
    u16* op = out + (size_t)e * R * C;
    #pragma unroll
    for (int i = 0; i < 16; ++i) {
      int flat = i * 256 + tid;
      int row = flat >> 6, col = flat & 63;
      t[row][col] = f2bf(ip[(size_t)(r0 + row) * C + c0 + col]);
    }
    __syncthreads();
    #pragma unroll
    for (int i = 0; i < 16; ++i) {
      int flat = i * 256 + tid;
      int orow = flat >> 6, ocol = flat & 63;     // out row = col-index, 128B stores
      op[(size_t)(c0 + orow) * R + r0 + ocol] = t[ocol][orow];
    }
    return;
  }

  // ---- logits: 4 tokens per block ----
  float* rwl = (float*)smem;
  for (int i = tid; i < N_EXP * HIDDEN / 4; i += 256)
    ((float4*)rwl)[i] = ((const float4*)rw)[i];
  __syncthreads();
  int w = tid >> 6, l = tid & 63;
  int t = x * 4 + w;
  const float* tp = tokens + (size_t)t * HIDDEN;
  u16* tb = tokb + (size_t)t * HIDDEN;
  float acc[8] = {0.f,0.f,0.f,0.f,0.f,0.f,0.f,0.f};
  #pragma unroll
  for (int it = 0; it < 4; ++it) {
    int k = it * 256 + l * 4;
    float4 tv = *(const float4*)&tp[k];
    ushort4 o;
    o.x = f2bf(tv.x); o.y = f2bf(tv.y); o.z = f2bf(tv.z); o.w = f2bf(tv.w);
    *(ushort4*)&tb[k] = o;
    #pragma unroll
    for (int e = 0; e < 8; ++e) {
      const float4 rv = *(const float4*)&rwl[e * HIDDEN + k];
      acc[e] += tv.x * rv.x + tv.y * rv.y + tv.z * rv.z + tv.w * rv.w;
    }
  }
  #pragma unroll
  for (int off = 32; off >= 1; off >>= 1) {
    #pragma unroll
    for (int e = 0; e < 8; ++e) acc[e] += __shfl_xor(acc[e], off);
  }
  if (l == 0) {
    float lg[8];
    #pragma unroll
    for (int e = 0; e < 8; ++e) lg[e] = acc[e] + rb[e];
    int b0 = 0; float v0 = lg[0];
    #pragma unroll
    for (int e = 1; e < 8; ++e) if (lg[e] > v0) { v0 = lg[e]; b0 = e; }
    int b1 = -1; float v1 = -3.4e38f;
    #pragma unroll
    for (int e = 0; e < 8; ++e) {
      if (e == b0) continue;
      if (lg[e] > v1) { v1 = lg[e]; b1 = e; }
    }
    float d = expf(v1 - v0);
    float p1 = d / (1.f + d);
    float p0 = 1.f - p1;
    e01[t * 2] = b0;   e01[t * 2 + 1] = b1;
    gates[t * 2] = p0; gates[t * 2 + 1] = p1;
  }
}

// ---------- parallel stable counting sort (3 phases, order == index-ascending) ----------
__global__ __launch_bounds__(256) void sortcnt_k(const int* __restrict__ e01,
                                                 int* __restrict__ bcnt) {
  __shared__ int wc[4][8];
  int b = blockIdx.x, tid = threadIdx.x, w = tid >> 6, l = tid & 63;
  int ei = e01[b * 256 + tid];
  #pragma unroll
  for (int e = 0; e < 8; ++e) {
    unsigned long long m = __ballot(ei == e);
    if (l == 0) wc[w][e] = __popcll(m);
  }
  __syncthreads();
  if (tid < 8)
    bcnt[tid * 32 + b] = wc[0][tid] + wc[1][tid] + wc[2][tid] + wc[3][tid];
}

__global__ void scan_k(const int* __restrict__ bcnt,
                       int* __restrict__ obase, int* __restrict__ cnt) {
  if (threadIdx.x == 0) {
    int ec[8];
    for (int e = 0; e < 8; ++e) {
      int s = 0;
      for (int b = 0; b < 32; ++b) { obase[e * 32 + b] = s; s += bcnt[e * 32 + b]; }
      ec[e] = s; cnt[e] = s;
    }
    int base = 0;
    for (int e = 0; e < 8; ++e) {
      for (int b = 0; b < 32; ++b) obase[e * 32 + b] += base;
      base += ec[e];
    }
  }
}

__global__ __launch_bounds__(256) void scatter_k(const int* __restrict__ e01,
                                                 const float* __restrict__ gates,
                                                 const int* __restrict__ obase,
                                                 int* __restrict__ rlt,
                                                 float* __restrict__ rlg,
                                                 int* __restrict__ rows2) {
  __shared__ int wc[4][8];
  __shared__ int wpre[4][8];
  int b = blockIdx.x, tid = threadIdx.x, w = tid >> 6, l = tid & 63;
  int i = b * 256 + tid;
  int ei = e01[i];
  unsigned long long ltm = (1ull << l) - 1ull;
  int lanerank = 0;
  #pragma unroll
  for (int e = 0; e < 8; ++e) {
    unsigned long long m = __ballot(ei == e);
    if (l == 0) wc[w][e] = __popcll(m);
    if (ei == e) lanerank = __popcll(m & ltm);
  }
  __syncthreads();
  if (tid < 8) {
    int s = 0;
    for (int ww = 0; ww < 4; ++ww) { wpre[ww][tid] = s; s += wc[ww][tid]; }
  }
  __syncthreads();
  int row = obase[ei * 32 + b] + wpre[w][ei] + lanerank;
  rlt[row] = i >> 1;
  rlg[row] = gates[i];
  rows2[i] = row;
}

// ======= R18/R20 winner: 128x64x64 tile; 512 thr / 8 waves (4M x 2N), wave tile 32x32 =======
// Named A0/A1 (16 KB) + B0/B1 (8 KB) = 48 KB -> 3 blocks/CU -> 24 waves/CU (6/SIMD).
// 3 glds16/thread/K-tile. XCD affinity: block b serves expert e = b&7.

#define STAGE(Ad, Bd, KT) {                                                      \
  glds16(ga[0] + (size_t)(KT) * 64, &Ad[threadIdx.x * 8]);                       \
  glds16(ga[1] + (size_t)(KT) * 64, &Ad[(512 + threadIdx.x) * 8]);               \
  glds16(gb0   + (size_t)(KT) * 64, &Bd[threadIdx.x * 8]);                       \
}

#define GEMM_TILE(As, Bs) {                                                      \
  _Pragma("unroll") for (int kk = 0; kk < 2; ++kk) {                             \
    short8 afr[2], bfr[2];                                                       \
    _Pragma("unroll") for (int i = 0; i < 2; ++i) {                              \
      afr[i] = *(const short8*)&As[oa[kk][i]];                                   \
      bfr[i] = *(const short8*)&Bs[ob[kk][i]];                                   \
    }                                                                            \
    _Pragma("unroll") for (int i = 0; i < 2; ++i)                                \
      _Pragma("unroll") for (int j = 0; j < 2; ++j)                              \
        acc[i][j] = __builtin_amdgcn_mfma_f32_16x16x32_bf16(                     \
            afr[i], bfr[j], acc[i][j], 0, 0, 0);                                 \
  }                                                                              \
}

#define FRAG_OFFSETS {                                                           \
  _Pragma("unroll") for (int kk = 0; kk < 2; ++kk) {                             \
    int cc = kk * 4 + lg;                                                        \
    _Pragma("unroll") for (int i = 0; i < 2; ++i) {                              \
      int Ra = wr * 32 + i * 16 + lr;                                            \
      oa[kk][i] = Ra * 64 + (cc ^ (Ra & 7)) * 8;                                 \
      int Rb = wc * 32 + i * 16 + lr;                                            \
      ob[kk][i] = Rb * 64 + (cc ^ (Rb & 7)) * 8;                                 \
    }                                                                            \
  }                                                                              \
}

// ---------- stage 1: h = gelu(tok_rows @ w1[e] + b1[e]) ----------
__global__ __launch_bounds__(512) void ffn1_k(const u16* __restrict__ tok,
                                              const u16* __restrict__ w1t,
                                              const float* __restrict__ b1,
                                              const int* __restrict__ rlt,
                                              const int* __restrict__ cnt,
                                              u16* __restrict__ h) {
  __shared__ __align__(16) short A0[8192];   // 128x64 bf16
  __shared__ __align__(16) short A1[8192];
  __shared__ __align__(16) short B0[4096];   // 64x64 bf16
  __shared__ __align__(16) short B1[4096];

  int tid = threadIdx.x, w = tid >> 6, l = tid & 63;
  int wr = w >> 1, wc = w & 1;               // 4M x 2N
  int lr = l & 15, lg = l >> 4;
  int oa[2][2], ob[2][2];
  FRAG_OFFSETS

  int e = blockIdx.x & 7;
  int rnk = blockIdx.x >> 3;
  int estr = gridDim.x >> 3;
  int m0 = 0;
  #pragma unroll
  for (int i = 0; i < 8; ++i) { int ci = cnt[i]; if (i < e) m0 += ci; }
  int ne = cnt[e];
  int mts = (ne + 127) >> 7;
  int NT_e = mts * (EXPAND / 64);            // mt-tiles x 32 nt

  for (int r = rnk; r < NT_e; r += estr) {
    int mt = r >> 5, nt = r & 31;            // nt-inner: consecutive ranks share A
    int m0g = m0 + mt * 128;
    int mrem = ne - mt * 128;

    const u16* ga[2]; const u16* gb0;
    #pragma unroll
    for (int c = 0; c < 2; ++c) {
      int flat = c * 512 + tid, rih = flat >> 3;   // 0..127
      int ch = (flat & 7) ^ (rih & 7);
      int tokid = rlt[m0g + ((rih < mrem) ? rih : 0)];
      ga[c] = tok + (size_t)tokid * HIDDEN + ch * 8;
    }
    {
      int rih = tid >> 3;                          // 0..63
      int ch = (tid & 7) ^ (rih & 7);
      int nrow = nt * 64 + rih;
      gb0 = w1t + (size_t)e * (EXPAND * HIDDEN) + (size_t)nrow * HIDDEN + ch * 8;
    }

    f32x4 acc[2][2] = {};
    STAGE(A0, B0, 0)
    __syncthreads();
    #pragma unroll 1
    for (int it = 0; it < 8; ++it) {               // NK = 16, 2 K-tiles/iter
      STAGE(A1, B1, 2 * it + 1)
      GEMM_TILE(A0, B0)
      __syncthreads();
      if (it < 7) STAGE(A0, B0, 2 * it + 2)
      GEMM_TILE(A1, B1)
      __syncthreads();
    }

    #pragma unroll
    for (int i = 0; i < 2; ++i) {
      #pragma unroll
      for (int rr = 0; rr < 4; ++rr) {
        int row = wr * 32 + i * 16 + lg * 4 + rr;
        if (row >= mrem) continue;
        size_t hrow = (size_t)(m0g + row) * EXPAND;
        #pragma unroll
        for (int j = 0; j < 2; ++j) {
          int col = nt * 64 + wc * 32 + j * 16 + lr;
          float x = acc[i][j][rr] + b1[e * EXPAND + col];
          h[hrow + col] = f2bf(gelu_tanh(x));
        }
      }
    }
  }
}

// ---------- stage 2: obuf[row] = bf16( gate * (h[row] @ w2[e] + b2[e]) ) ----------
__global__ __launch_bounds__(512) void ffn2_k(const u16* __restrict__ h,
                                              const u16* __restrict__ w2t,
                                              const float* __restrict__ b2,
                                              const float* __restrict__ rlg,
                                              const int* __restrict__ cnt,
                                              u16* __restrict__ obuf) {
  __shared__ __align__(16) short A0[8192];
  __shared__ __align__(16) short A1[8192];
  __shared__ __align__(16) short B0[4096];
  __shared__ __align__(16) short B1[4096];

  int tid = threadIdx.x, w = tid >> 6, l = tid & 63;
  int wr = w >> 1, wc = w & 1;
  int lr = l & 15, lg = l >> 4;
  int oa[2][2], ob[2][2];
  FRAG_OFFSETS

  int e = blockIdx.x & 7;
  int rnk = blockIdx.x >> 3;
  int estr = gridDim.x >> 3;
  int m0 = 0;
  #pragma unroll
  for (int i = 0; i < 8; ++i) { int ci = cnt[i]; if (i < e) m0 += ci; }
  int ne = cnt[e];
  int mts = (ne + 127) >> 7;
  int NT_e = mts * (HIDDEN / 64);            // mt-tiles x 16 nt

  for (int r = rnk; r < NT_e; r += estr) {
    int mt = r >> 4, nt = r & 15;
    int m0g = m0 + mt * 128;
    int mrem = ne - mt * 128;

    const u16* ga[2]; const u16* gb0;
    #pragma unroll
    for (int c = 0; c < 2; ++c) {
      int flat = c * 512 + tid, rih = flat >> 3;
      int ch = (flat & 7) ^ (rih & 7);
      int rowg = m0g + ((rih < mrem) ? rih : 0);
      ga[c] = h + (size_t)rowg * EXPAND + ch * 8;
    }
    {
      int rih = tid >> 3;
      int ch = (tid & 7) ^ (rih & 7);
      int nrow = nt * 64 + rih;
      gb0 = w2t + (size_t)e * (HIDDEN * EXPAND) + (size_t)nrow * EXPAND + ch * 8;
    }

    f32x4 acc[2][2] = {};
    STAGE(A0, B0, 0)
    __syncthreads();
    #pragma unroll 1
    for (int it = 0; it < 16; ++it) {              // NK = 32, 2 K-tiles/iter
      STAGE(A1, B1, 2 * it + 1)
      GEMM_TILE(A0, B0)
      __syncthreads();
      if (it < 15) STAGE(A0, B0, 2 * it + 2)
      GEMM_TILE(A1, B1)
      __syncthreads();
    }

    #pragma unroll
    for (int i = 0; i < 2; ++i) {
      #pragma unroll
      for (int rr = 0; rr < 4; ++rr) {
        int row = wr * 32 + i * 16 + lg * 4 + rr;
        if (row >= mrem) continue;
        float gate = rlg[m0g + row];
        size_t orow = (size_t)(m0g + row) * HIDDEN;
        #pragma unroll
        for (int j = 0; j < 2; ++j) {
          int col = nt * 64 + wc * 32 + j * 16 + lr;
          obuf[orow + col] = f2bf((acc[i][j][rr] + b2[e * HIDDEN + col]) * gate);
        }
      }
    }
  }
}

// ---------- combine: out[t] = obuf[row0(t)] + obuf[row1(t)]  (bf16 in, fp32 out) ----------
__global__ __launch_bounds__(256) void combine_k(const u16* __restrict__ obuf,
                                                 const int* __restrict__ rows2,
                                                 float* __restrict__ out) {
  int t = blockIdx.x, c = threadIdx.x;
  int r0 = rows2[t * 2], r1 = rows2[t * 2 + 1];
  ushort4 a = ((const ushort4*)obuf)[(size_t)r0 * 256 + c];
  ushort4 b = ((const ushort4*)obuf)[(size_t)r1 * 256 + c];
  float4 o;
  o.x = bf2f(a.x) + bf2f(b.x);
  o.y = bf2f(a.y) + bf2f(b.y);
  o.z = bf2f(a.z) + bf2f(b.z);
  o.w = bf2f(a.w) + bf2f(b.w);
  ((float4*)out)[(size_t)t * 256 + c] = o;
}

extern "C" void kernel_launch(void* const* d_in, const int* in_sizes, int n_in,
                              void* d_out, int out_size, void* d_ws, size_t ws_size,
                              hipStream_t stream) {
  const float* tokens   = (const float*)d_in[0];
  const float* router_w = (const float*)d_in[1];
  const float* router_b = (const float*)d_in[2];
  const float* w1       = (const float*)d_in[3];
  const float* b1       = (const float*)d_in[4];
  const float* w2       = (const float*)d_in[5];
  const float* b2       = (const float*)d_in[6];
  float* out = (float*)d_out;

  char* ws = (char*)d_ws;
  u16*   tokb  = (u16*)(ws + TOKB_OFF);
  u16*   w1t   = (u16*)(ws + W1T_OFF);
  u16*   obuf  = (u16*)(ws + OBUF_OFF);
  u16*   w2t   = (u16*)(ws + W2T_OFF);
  u16*   h     = (u16*)(ws + H_OFF);
  int*   rlt   = (int*)(ws + RLT_OFF);
  float* rlg   = (float*)(ws + RLG_OFF);
  int*   cnt   = (int*)(ws + CNT_OFF);
  int*   e01   = (int*)(ws + E01_OFF);
  float* gates = (float*)(ws + GATE_OFF);
  int*   rows2 = (int*)(ws + ROWS2_OFF);
  int*   bcnt  = (int*)(ws + BCNT_OFF);
  int*   obase = (int*)(ws + OBASE_OFF);

  prep_k<<<9216, 256, 0, stream>>>(w1, w1t, w2, w2t,
                                   tokens, router_w, router_b, tokb, e01, gates);
  sortcnt_k<<<32, 256, 0, stream>>>(e01, bcnt);
  scan_k<<<1, 64, 0, stream>>>(bcnt, obase, cnt);
  scatter_k<<<32, 256, 0, stream>>>(e01, gates, obase, rlt, rlg, rows2);
  ffn1_k<<<2048, 512, 0, stream>>>(tokb, w1t, b1, rlt, cnt, h);
  ffn2_k<<<1024, 512, 0, stream>>>(h, w2t, b2, rlg, cnt, obuf);
  combine_k<<<N_TOKENS, 256, 0, stream>>>(obuf, rows2, out);
}

// Round 23
// 190.945 us; speedup vs baseline: 1.1637x; 1.0144x over previous
//
#include <hip/hip_runtime.h>
#include <hip/hip_bf16.h>

typedef unsigned short u16;
typedef __attribute__((ext_vector_type(8))) short short8;
typedef __attribute__((ext_vector_type(4))) float f32x4;

#define N_TOKENS 4096
#define HIDDEN   1024
#define N_EXP    8
#define EXPAND   2048

// ---------- workspace layout (bytes) ----------
#define TOKB_OFF  0ull                   // bf16 tokens      [4096][1024]    8,388,608
#define W1T_OFF   8388608ull             // bf16 w1^T        [8][2048][1024] 33,554,432
#define OBUF_OFF  8388608ull             // bf16 obuf        [8192][1024]    16,777,216 (reuses w1t after ffn1)
#define W2T_OFF   41943040ull            // bf16 w2^T        [8][1024][2048] 33,554,432
#define H_OFF     75497472ull            // bf16 h           [8192][2048]    33,554,432
#define RLT_OFF   109051904ull           // int rowlist_token[8192]
#define RLG_OFF   109084672ull           // float rowlist_gate[8192]
#define CNT_OFF   109117440ull           // int cnt[8]
#define E01_OFF   109117472ull           // int e01[4096][2]
#define GATE_OFF  109183008ull           // float gates[4096][2]
#define ROWS2_OFF 109215776ull           // int rows2[4096][2]
#define BCNT_OFF  109248544ull           // int bcnt[8][32]
#define OBASE_OFF 109249568ull           // int obase[8][32]

__device__ __forceinline__ u16 f2bf(float f) {
  union { float f; unsigned u; } v; v.f = f;
  unsigned r = v.u + 0x7fffu + ((v.u >> 16) & 1u);   // round-to-nearest-even
  return (u16)(r >> 16);
}

__device__ __forceinline__ float bf2f(u16 b) {
  union { unsigned u; float f; } v; v.u = ((unsigned)b) << 16;
  return v.f;
}

__device__ __forceinline__ void glds16(const void* g, void* l) {
  __builtin_amdgcn_global_load_lds(
      (const __attribute__((address_space(1))) void*)g,
      (__attribute__((address_space(3))) void*)l, 16, 0, 0);
}

__device__ __forceinline__ float gelu_tanh(float x) {
  float u = x * (0.7978845608f + 0.0356774081f * x * x);
  float t = __expf(-2.0f * fabsf(u));
  float th = (1.0f - t) / (1.0f + t);
  th = (u >= 0.0f) ? th : -th;
  return 0.5f * x * (1.0f + th);
}

// ---------- prep: logits (blocks [0,1024)) + w1 transpose ([1024,5120)) ----------
// w2 transpose is deferred into ffn1_k's extra blocks (overlaps the GEMM).
__global__ __launch_bounds__(256) void prep_k(const float* __restrict__ w1,
                                              u16* __restrict__ w1t,
                                              const float* __restrict__ tokens,
                                              const float* __restrict__ rw,
                                              const float* __restrict__ rb,
                                              u16* __restrict__ tokb,
                                              int* __restrict__ e01,
                                              float* __restrict__ gates) {
  __shared__ __align__(16) char smem[32768];
  int x = blockIdx.x;
  int tid = threadIdx.x;

  if (x >= 1024) {
    // ---- w1 transpose tile: idx in [0, 4096) ----
    u16 (*t)[66] = (u16 (*)[66])smem;
    int idx = x - 1024;
    int e = idx >> 9; int rem = idx & 511;
    int cx = rem & 31, ry = rem >> 5;      // w1: C/64=32, R/64=16
    const int R = HIDDEN, C = EXPAND;
    int c0 = cx * 64, r0 = ry * 64;
    const float* ip = w1 + (size_t)e * R * C;
    u16* op = w1t + (size_t)e * R * C;
    #pragma unroll
    for (int i = 0; i < 16; ++i) {
      int flat = i * 256 + tid;
      int row = flat >> 6, col = flat & 63;
      t[row][col] = f2bf(ip[(size_t)(r0 + row) * C + c0 + col]);
    }
    __syncthreads();
    #pragma unroll
    for (int i = 0; i < 16; ++i) {
      int flat = i * 256 + tid;
      int orow = flat >> 6, ocol = flat & 63;     // out row = col-index, 128B stores
      op[(size_t)(c0 + orow) * R + r0 + ocol] = t[ocol][orow];
    }
    return;
  }

  // ---- logits: 4 tokens per block ----
  float* rwl = (float*)smem;
  for (int i = tid; i < N_EXP * HIDDEN / 4; i += 256)
    ((float4*)rwl)[i] = ((const float4*)rw)[i];
  __syncthreads();
  int w = tid >> 6, l = tid & 63;
  int t = x * 4 + w;
  const float* tp = tokens + (size_t)t * HIDDEN;
  u16* tb = tokb + (size_t)t * HIDDEN;
  float acc[8] = {0.f,0.f,0.f,0.f,0.f,0.f,0.f,0.f};
  #pragma unroll
  for (int it = 0; it < 4; ++it) {
    int k = it * 256 + l * 4;
    float4 tv = *(const float4*)&tp[k];
    ushort4 o;
    o.x = f2bf(tv.x); o.y = f2bf(tv.y); o.z = f2bf(tv.z); o.w = f2bf(tv.w);
    *(ushort4*)&tb[k] = o;
    #pragma unroll
    for (int e = 0; e < 8; ++e) {
      const float4 rv = *(const float4*)&rwl[e * HIDDEN + k];
      acc[e] += tv.x * rv.x + tv.y * rv.y + tv.z * rv.z + tv.w * rv.w;
    }
  }
  #pragma unroll
  for (int off = 32; off >= 1; off >>= 1) {
    #pragma unroll
    for (int e = 0; e < 8; ++e) acc[e] += __shfl_xor(acc[e], off);
  }
  if (l == 0) {
    float lg[8];
    #pragma unroll
    for (int e = 0; e < 8; ++e) lg[e] = acc[e] + rb[e];
    int b0 = 0; float v0 = lg[0];
    #pragma unroll
    for (int e = 1; e < 8; ++e) if (lg[e] > v0) { v0 = lg[e]; b0 = e; }
    int b1 = -1; float v1 = -3.4e38f;
    #pragma unroll
    for (int e = 0; e < 8; ++e) {
      if (e == b0) continue;
      if (lg[e] > v1) { v1 = lg[e]; b1 = e; }
    }
    float d = expf(v1 - v0);
    float p1 = d / (1.f + d);
    float p0 = 1.f - p1;
    e01[t * 2] = b0;   e01[t * 2 + 1] = b1;
    gates[t * 2] = p0; gates[t * 2 + 1] = p1;
  }
}

// ---------- parallel stable counting sort (3 phases, order == index-ascending) ----------
__global__ __launch_bounds__(256) void sortcnt_k(const int* __restrict__ e01,
                                                 int* __restrict__ bcnt) {
  __shared__ int wc[4][8];
  int b = blockIdx.x, tid = threadIdx.x, w = tid >> 6, l = tid & 63;
  int ei = e01[b * 256 + tid];
  #pragma unroll
  for (int e = 0; e < 8; ++e) {
    unsigned long long m = __ballot(ei == e);
    if (l == 0) wc[w][e] = __popcll(m);
  }
  __syncthreads();
  if (tid < 8)
    bcnt[tid * 32 + b] = wc[0][tid] + wc[1][tid] + wc[2][tid] + wc[3][tid];
}

__global__ void scan_k(const int* __restrict__ bcnt,
                       int* __restrict__ obase, int* __restrict__ cnt) {
  if (threadIdx.x == 0) {
    int ec[8];
    for (int e = 0; e < 8; ++e) {
      int s = 0;
      for (int b = 0; b < 32; ++b) { obase[e * 32 + b] = s; s += bcnt[e * 32 + b]; }
      ec[e] = s; cnt[e] = s;
    }
    int base = 0;
    for (int e = 0; e < 8; ++e) {
      for (int b = 0; b < 32; ++b) obase[e * 32 + b] += base;
      base += ec[e];
    }
  }
}

__global__ __launch_bounds__(256) void scatter_k(const int* __restrict__ e01,
                                                 const float* __restrict__ gates,
                                                 const int* __restrict__ obase,
                                                 int* __restrict__ rlt,
                                                 float* __restrict__ rlg,
                                                 int* __restrict__ rows2) {
  __shared__ int wc[4][8];
  __shared__ int wpre[4][8];
  int b = blockIdx.x, tid = threadIdx.x, w = tid >> 6, l = tid & 63;
  int i = b * 256 + tid;
  int ei = e01[i];
  unsigned long long ltm = (1ull << l) - 1ull;
  int lanerank = 0;
  #pragma unroll
  for (int e = 0; e < 8; ++e) {
    unsigned long long m = __ballot(ei == e);
    if (l == 0) wc[w][e] = __popcll(m);
    if (ei == e) lanerank = __popcll(m & ltm);
  }
  __syncthreads();
  if (tid < 8) {
    int s = 0;
    for (int ww = 0; ww < 4; ++ww) { wpre[ww][tid] = s; s += wc[ww][tid]; }
  }
  __syncthreads();
  int row = obase[ei * 32 + b] + wpre[w][ei] + lanerank;
  rlt[row] = i >> 1;
  rlg[row] = gates[i];
  rows2[i] = row;
}

// ======= R18/R20 winner: 128x64x64 tile; 512 thr / 8 waves (4M x 2N), wave tile 32x32 =======
// Named A0/A1 (16 KB) + B0/B1 (8 KB) = 48 KB -> 3 blocks/CU -> 24 waves/CU (6/SIMD).
// 3 glds16/thread/K-tile. XCD affinity: block b serves expert e = b&7.

#define STAGE(Ad, Bd, KT) {                                                      \
  glds16(ga[0] + (size_t)(KT) * 64, &Ad[threadIdx.x * 8]);                       \
  glds16(ga[1] + (size_t)(KT) * 64, &Ad[(512 + threadIdx.x) * 8]);               \
  glds16(gb0   + (size_t)(KT) * 64, &Bd[threadIdx.x * 8]);                       \
}

#define GEMM_TILE(As, Bs) {                                                      \
  _Pragma("unroll") for (int kk = 0; kk < 2; ++kk) {                             \
    short8 afr[2], bfr[2];                                                       \
    _Pragma("unroll") for (int i = 0; i < 2; ++i) {                              \
      afr[i] = *(const short8*)&As[oa[kk][i]];                                   \
      bfr[i] = *(const short8*)&Bs[ob[kk][i]];                                   \
    }                                                                            \
    _Pragma("unroll") for (int i = 0; i < 2; ++i)                                \
      _Pragma("unroll") for (int j = 0; j < 2; ++j)                              \
        acc[i][j] = __builtin_amdgcn_mfma_f32_16x16x32_bf16(                     \
            afr[i], bfr[j], acc[i][j], 0, 0, 0);                                 \
  }                                                                              \
}

#define FRAG_OFFSETS {                                                           \
  _Pragma("unroll") for (int kk = 0; kk < 2; ++kk) {                             \
    int cc = kk * 4 + lg;                                                        \
    _Pragma("unroll") for (int i = 0; i < 2; ++i) {                              \
      int Ra = wr * 32 + i * 16 + lr;                                            \
      oa[kk][i] = Ra * 64 + (cc ^ (Ra & 7)) * 8;                                 \
      int Rb = wc * 32 + i * 16 + lr;                                            \
      ob[kk][i] = Rb * 64 + (cc ^ (Rb & 7)) * 8;                                 \
    }                                                                            \
  }                                                                              \
}

// ---------- stage 1: GEMM blocks [0,2048) + w2-transpose blocks [2048,6144) ----------
__global__ __launch_bounds__(512) void ffn1_k(const u16* __restrict__ tok,
                                              const u16* __restrict__ w1t,
                                              const float* __restrict__ b1,
                                              const int* __restrict__ rlt,
                                              const int* __restrict__ cnt,
                                              u16* __restrict__ h,
                                              const float* __restrict__ w2,
                                              u16* __restrict__ w2t) {
  __shared__ __align__(16) short A0[8192];   // 128x64 bf16 (aliased by transpose)
  __shared__ __align__(16) short A1[8192];
  __shared__ __align__(16) short B0[4096];   // 64x64 bf16
  __shared__ __align__(16) short B1[4096];

  int tid = threadIdx.x;

  if (blockIdx.x >= 2048) {
    // ---- w2 transpose tile: idx in [0, 4096); 512 threads, 8 iters ----
    u16 (*t)[66] = (u16 (*)[66])A0;          // 64*66*2 = 8448 B <= 16 KB
    int idx = blockIdx.x - 2048;
    int e = idx >> 9; int rem = idx & 511;
    int cx = rem & 15, ry = rem >> 4;        // w2: C/64=16, R/64=32
    const int R = EXPAND, C = HIDDEN;
    int c0 = cx * 64, r0 = ry * 64;
    const float* ip = w2 + (size_t)e * R * C;
    u16* op = w2t + (size_t)e * R * C;
    #pragma unroll
    for (int i = 0; i < 8; ++i) {
      int flat = i * 512 + tid;
      int row = flat >> 6, col = flat & 63;
      t[row][col] = f2bf(ip[(size_t)(r0 + row) * C + c0 + col]);
    }
    __syncthreads();
    #pragma unroll
    for (int i = 0; i < 8; ++i) {
      int flat = i * 512 + tid;
      int orow = flat >> 6, ocol = flat & 63;
      op[(size_t)(c0 + orow) * R + r0 + ocol] = t[ocol][orow];
    }
    return;
  }

  int w = tid >> 6, l = tid & 63;
  int wr = w >> 1, wc = w & 1;               // 4M x 2N
  int lr = l & 15, lg = l >> 4;
  int oa[2][2], ob[2][2];
  FRAG_OFFSETS

  int e = blockIdx.x & 7;
  int rnk = blockIdx.x >> 3;
  const int estr = 256;                      // 2048 GEMM blocks / 8 experts
  int m0 = 0;
  #pragma unroll
  for (int i = 0; i < 8; ++i) { int ci = cnt[i]; if (i < e) m0 += ci; }
  int ne = cnt[e];
  int mts = (ne + 127) >> 7;
  int NT_e = mts * (EXPAND / 64);            // mt-tiles x 32 nt

  for (int r = rnk; r < NT_e; r += estr) {
    int mt = r >> 5, nt = r & 31;            // nt-inner: consecutive ranks share A
    int m0g = m0 + mt * 128;
    int mrem = ne - mt * 128;

    const u16* ga[2]; const u16* gb0;
    #pragma unroll
    for (int c = 0; c < 2; ++c) {
      int flat = c * 512 + tid, rih = flat >> 3;   // 0..127
      int ch = (flat & 7) ^ (rih & 7);
      int tokid = rlt[m0g + ((rih < mrem) ? rih : 0)];
      ga[c] = tok + (size_t)tokid * HIDDEN + ch * 8;
    }
    {
      int rih = tid >> 3;                          // 0..63
      int ch = (tid & 7) ^ (rih & 7);
      int nrow = nt * 64 + rih;
      gb0 = w1t + (size_t)e * (EXPAND * HIDDEN) + (size_t)nrow * HIDDEN + ch * 8;
    }

    f32x4 acc[2][2] = {};
    STAGE(A0, B0, 0)
    __syncthreads();
    #pragma unroll 1
    for (int it = 0; it < 8; ++it) {               // NK = 16, 2 K-tiles/iter
      STAGE(A1, B1, 2 * it + 1)
      GEMM_TILE(A0, B0)
      __syncthreads();
      if (it < 7) STAGE(A0, B0, 2 * it + 2)
      GEMM_TILE(A1, B1)
      __syncthreads();
    }

    #pragma unroll
    for (int i = 0; i < 2; ++i) {
      #pragma unroll
      for (int rr = 0; rr < 4; ++rr) {
        int row = wr * 32 + i * 16 + lg * 4 + rr;
        if (row >= mrem) continue;
        size_t hrow = (size_t)(m0g + row) * EXPAND;
        #pragma unroll
        for (int j = 0; j < 2; ++j) {
          int col = nt * 64 + wc * 32 + j * 16 + lr;
          float x = acc[i][j][rr] + b1[e * EXPAND + col];
          h[hrow + col] = f2bf(gelu_tanh(x));
        }
      }
    }
  }
}

// ---------- stage 2: obuf[row] = bf16( gate * (h[row] @ w2[e] + b2[e]) ) ----------
__global__ __launch_bounds__(512) void ffn2_k(const u16* __restrict__ h,
                                              const u16* __restrict__ w2t,
                                              const float* __restrict__ b2,
                                              const float* __restrict__ rlg,
                                              const int* __restrict__ cnt,
                                              u16* __restrict__ obuf) {
  __shared__ __align__(16) short A0[8192];
  __shared__ __align__(16) short A1[8192];
  __shared__ __align__(16) short B0[4096];
  __shared__ __align__(16) short B1[4096];

  int tid = threadIdx.x, w = tid >> 6, l = tid & 63;
  int wr = w >> 1, wc = w & 1;
  int lr = l & 15, lg = l >> 4;
  int oa[2][2], ob[2][2];
  FRAG_OFFSETS

  int e = blockIdx.x & 7;
  int rnk = blockIdx.x >> 3;
  int estr = gridDim.x >> 3;
  int m0 = 0;
  #pragma unroll
  for (int i = 0; i < 8; ++i) { int ci = cnt[i]; if (i < e) m0 += ci; }
  int ne = cnt[e];
  int mts = (ne + 127) >> 7;
  int NT_e = mts * (HIDDEN / 64);            // mt-tiles x 16 nt

  for (int r = rnk; r < NT_e; r += estr) {
    int mt = r >> 4, nt = r & 15;
    int m0g = m0 + mt * 128;
    int mrem = ne - mt * 128;

    const u16* ga[2]; const u16* gb0;
    #pragma unroll
    for (int c = 0; c < 2; ++c) {
      int flat = c * 512 + tid, rih = flat >> 3;
      int ch = (flat & 7) ^ (rih & 7);
      int rowg = m0g + ((rih < mrem) ? rih : 0);
      ga[c] = h + (size_t)rowg * EXPAND + ch * 8;
    }
    {
      int rih = tid >> 3;
      int ch = (tid & 7) ^ (rih & 7);
      int nrow = nt * 64 + rih;
      gb0 = w2t + (size_t)e * (HIDDEN * EXPAND) + (size_t)nrow * EXPAND + ch * 8;
    }

    f32x4 acc[2][2] = {};
    STAGE(A0, B0, 0)
    __syncthreads();
    #pragma unroll 1
    for (int it = 0; it < 16; ++it) {              // NK = 32, 2 K-tiles/iter
      STAGE(A1, B1, 2 * it + 1)
      GEMM_TILE(A0, B0)
      __syncthreads();
      if (it < 15) STAGE(A0, B0, 2 * it + 2)
      GEMM_TILE(A1, B1)
      __syncthreads();
    }

    #pragma unroll
    for (int i = 0; i < 2; ++i) {
      #pragma unroll
      for (int rr = 0; rr < 4; ++rr) {
        int row = wr * 32 + i * 16 + lg * 4 + rr;
        if (row >= mrem) continue;
        float gate = rlg[m0g + row];
        size_t orow = (size_t)(m0g + row) * HIDDEN;
        #pragma unroll
        for (int j = 0; j < 2; ++j) {
          int col = nt * 64 + wc * 32 + j * 16 + lr;
          obuf[orow + col] = f2bf((acc[i][j][rr] + b2[e * HIDDEN + col]) * gate);
        }
      }
    }
  }
}

// ---------- combine: out[t] = obuf[row0(t)] + obuf[row1(t)]  (bf16 in, fp32 out) ----------
__global__ __launch_bounds__(256) void combine_k(const u16* __restrict__ obuf,
                                                 const int* __restrict__ rows2,
                                                 float* __restrict__ out) {
  int t = blockIdx.x, c = threadIdx.x;
  int r0 = rows2[t * 2], r1 = rows2[t * 2 + 1];
  ushort4 a = ((const ushort4*)obuf)[(size_t)r0 * 256 + c];
  ushort4 b = ((const ushort4*)obuf)[(size_t)r1 * 256 + c];
  float4 o;
  o.x = bf2f(a.x) + bf2f(b.x);
  o.y = bf2f(a.y) + bf2f(b.y);
  o.z = bf2f(a.z) + bf2f(b.z);
  o.w = bf2f(a.w) + bf2f(b.w);
  ((float4*)out)[(size_t)t * 256 + c] = o;
}

extern "C" void kernel_launch(void* const* d_in, const int* in_sizes, int n_in,
                              void* d_out, int out_size, void* d_ws, size_t ws_size,
                              hipStream_t stream) {
  const float* tokens   = (const float*)d_in[0];
  const float* router_w = (const float*)d_in[1];
  const float* router_b = (const float*)d_in[2];
  const float* w1       = (const float*)d_in[3];
  const float* b1       = (const float*)d_in[4];
  const float* w2       = (const float*)d_in[5];
  const float* b2       = (const float*)d_in[6];
  float* out = (float*)d_out;

  char* ws = (char*)d_ws;
  u16*   tokb  = (u16*)(ws + TOKB_OFF);
  u16*   w1t   = (u16*)(ws + W1T_OFF);
  u16*   obuf  = (u16*)(ws + OBUF_OFF);
  u16*   w2t   = (u16*)(ws + W2T_OFF);
  u16*   h     = (u16*)(ws + H_OFF);
  int*   rlt   = (int*)(ws + RLT_OFF);
  float* rlg   = (float*)(ws + RLG_OFF);
  int*   cnt   = (int*)(ws + CNT_OFF);
  int*   e01   = (int*)(ws + E01_OFF);
  float* gates = (float*)(ws + GATE_OFF);
  int*   rows2 = (int*)(ws + ROWS2_OFF);
  int*   bcnt  = (int*)(ws + BCNT_OFF);
  int*   obase = (int*)(ws + OBASE_OFF);

  prep_k<<<5120, 256, 0, stream>>>(w1, w1t, tokens, router_w, router_b,
                                   tokb, e01, gates);
  sortcnt_k<<<32, 256, 0, stream>>>(e01, bcnt);
  scan_k<<<1, 64, 0, stream>>>(bcnt, obase, cnt);
  scatter_k<<<32, 256, 0, stream>>>(e01, gates, obase, rlt, rlg, rows2);
  ffn1_k<<<6144, 512, 0, stream>>>(tokb, w1t, b1, rlt, cnt, h, w2, w2t);
  ffn2_k<<<1024, 512, 0, stream>>>(h, w2t, b2, rlg, cnt, obuf);
  combine_k<<<N_TOKENS, 256, 0, stream>>>(obuf, rows2, out);
}